// Round 10
// baseline (1442.114 us; speedup 1.0000x reference)
//
#include <hip/hip_runtime.h>
#include <hip/hip_bf16.h>

// ---------------- constants ----------------
constexpr int NN = 40000;   // nodes
constexpr int NE = 400000;  // edges (before self-loops)
constexpr int NSLAB = 20000;
constexpr int MPAD = 20096; // 157 * 128 (M-tile overrun padding; 314 * 64)
constexpr int SCB = 256;    // scan blocks
constexpr int SCHUNK = (NN + SCB - 1) / SCB;   // 157 (<= 256)
constexpr int NPB = 512;    // bn_partial blocks (rows of `partial`)

__device__ __forceinline__ unsigned short f2bf(float f) {
    unsigned int u = __float_as_uint(f);
    unsigned int r = (u + 0x7FFFu + ((u >> 16) & 1u)) >> 16;
    return (unsigned short)r;
}

// packed f32x2 -> bf16x2, RTNE (bit-identical to f2bf pairs), 1 instruction
__device__ __forceinline__ unsigned int cvt_pk_bf16(float a, float b) {
    unsigned int r;
    asm("v_cvt_pk_bf16_f32 %0, %1, %2" : "=v"(r) : "v"(a), "v"(b));
    return r;
}

// async global->LDS 16B: no VGPR round-trip, loads issue back-to-back.
__device__ __forceinline__ void load_lds16(const unsigned short* g, unsigned short* l) {
    __builtin_amdgcn_global_load_lds(
        (const __attribute__((address_space(1))) unsigned int*)(g),
        (__attribute__((address_space(3))) unsigned int*)(l), 16, 0, 0);
}

typedef __attribute__((ext_vector_type(8))) short bf16x8;
typedef __attribute__((ext_vector_type(4))) float f32x4;
typedef __attribute__((ext_vector_type(2))) float floatx2;

// ---------------- BN ----------------
// L1 only: stats of the raw input x. L2-L4 stats are produced by the previous
// layer's epilogue (reduce_parts_stats / FB-gemm stats) — r25.
__global__ void bn_partial(const float* __restrict__ x, int N, int C,
                           float* __restrict__ partial) {
    int ch = threadIdx.x;            // blockDim = 128, C <= 128
    if (ch >= C) return;
    float s = 0.f, sq = 0.f;
    for (int n = blockIdx.x; n < N; n += gridDim.x) {
        float v = x[(size_t)n * C + ch];
        s += v; sq += v * v;
    }
    partial[(size_t)blockIdx.x * 2 * C + ch]     = s;
    partial[(size_t)blockIdx.x * 2 * C + C + ch] = sq;
}

// fused finalize + apply: every block derives scale/shift from `partial`
// (nb entries of layout [b][2][CIN], runtime nb; two half-sums), block 0
// publishes for gemm_bn; then grid-stride packed bf16 apply.
template <int CIN, int CP>
__global__ __launch_bounds__(256) void bn_apply_f(const float* __restrict__ x,
                                                  const float* __restrict__ partial,
                                                  int nb,
                                                  const float* __restrict__ g,
                                                  const float* __restrict__ be,
                                                  float* __restrict__ scale_g,
                                                  float* __restrict__ shift_g,
                                                  unsigned short* __restrict__ xbn) {
    __shared__ float hs[2][128], hq[2][128];
    __shared__ float sc_l[CP], sh_l[CP];
    const int tid = threadIdx.x;
    const int half = tid >> 7, ch = tid & 127;
    if (ch < CIN) {
        int b0 = half ? (nb >> 1) : 0;
        int b1 = half ? nb : (nb >> 1);
        float s = 0.f, sq = 0.f;
        for (int b = b0; b < b1; ++b) {
            s  += partial[(size_t)b * 2 * CIN + ch];
            sq += partial[(size_t)b * 2 * CIN + CIN + ch];
        }
        hs[half][ch] = s; hq[half][ch] = sq;
    }
    __syncthreads();
    if (tid < CP) {
        float sc = 0.f, sh = 0.f;
        if (tid < CIN) {
            float s  = hs[0][tid] + hs[1][tid];
            float sq = hq[0][tid] + hq[1][tid];
            float mean = s / (float)NN;
            float var  = sq / (float)NN - mean * mean;
            float inv  = rsqrtf(var + 1e-5f);
            sc = g[tid] * inv;
            sh = be[tid] - mean * sc;
            if (blockIdx.x == 0) { scale_g[tid] = sc; shift_g[tid] = sh; }
        }
        sc_l[tid] = sc; sh_l[tid] = sh;
    }
    __syncthreads();
    const int total = NN * (CP / 2);
    for (int idx = blockIdx.x * 256 + tid; idx < total; idx += 256 * gridDim.x) {
        int n = idx / (CP / 2), c2 = idx % (CP / 2);
        int c = 2 * c2;
        float v0 = 0.f, v1 = 0.f;
        if (c < CIN)     v0 = sc_l[c] * x[(size_t)n * CIN + c] + sh_l[c];
        if (c + 1 < CIN) v1 = sc_l[c + 1] * x[(size_t)n * CIN + c + 1] + sh_l[c + 1];
        reinterpret_cast<unsigned int*>(xbn)[idx] = cvt_pk_bf16(v0, v1);
    }
}

// ---------------- fused weight prep for ALL layers in ONE dispatch (r20) ----------
struct PrepLayer {
    const float* W; const float* as_; const float* ad_;
    float* Wf; unsigned short* Wft; unsigned short* Wt;
    int CIN, CP, COUT, NP, bbase;
};
struct PrepArgs { PrepLayer L[4]; int nb; };

__global__ void prep_all(PrepArgs A) {
    int bid = blockIdx.x;
    int li = 0;
#pragma unroll
    for (int i = 1; i < 4; ++i)
        if (bid >= A.L[i].bbase) li = i;
    const PrepLayer& P = A.L[li];
    const int CIN = P.CIN, CP = P.CP, COUT = P.COUT;
    int b = bid - P.bbase;
    int tid = threadIdx.x;
    if (b < CP) {
        int cin = b;
        if (tid < 64) {
            int j = tid, h = j & 31;
            float s = 0.f;
            if (cin < CIN) {
                const float* a = (j < 32) ? P.as_ : P.ad_;
                const float* wrow = P.W + (size_t)cin * 32 * COUT + (size_t)h * COUT;
                const float* arow = a + (size_t)h * COUT;
                for (int c = 0; c < COUT; ++c) s += wrow[c] * arow[c];
            }
            P.Wf[cin * 64 + j] = s;
            P.Wft[j * CP + cin] = f2bf(s);
        }
    } else {
        int c = b - CP;   // [0, NP)
        for (int kk = tid; kk < 32 * CP; kk += blockDim.x) {
            int h = kk / CP, k = kk % CP;
            float v = 0.f;
            if (k < CIN && c < COUT)
                v = P.W[(size_t)k * (32 * COUT) + h * COUT + c] * (1.f / 32.f);
            P.Wt[(size_t)c * (32 * CP) + kk] = f2bf(v);
        }
    }
}

// ---------------- MFMA score GEMM: Sbuf[n, 0:64] = xbn[n,:] @ Wft^T ------------------
template <int CPK>
__global__ __launch_bounds__(256) void gemm_s(const unsigned short* __restrict__ xbn,
                                              const unsigned short* __restrict__ Wft,
                                              float* __restrict__ Sbuf) {
    constexpr int NC = CPK / 32;
    __shared__ unsigned short Ab[64 * 32];
    __shared__ unsigned short Bb[64 * 32];
    const int m0 = blockIdx.x * 64;
    const int tid = threadIdx.x;
    const int wv = tid >> 6, lane = tid & 63;
    const int mm = lane & 15, quad = lane >> 4;
    f32x4 acc[4];
#pragma unroll
    for (int t = 0; t < 4; ++t) acc[t] = f32x4{0.f, 0.f, 0.f, 0.f};

    for (int c = 0; c < NC; ++c) {
        int row = tid >> 2, gc = tid & 3;
        load_lds16(xbn + (size_t)(m0 + row) * CPK + c * 32 + gc * 8, Ab + (size_t)tid * 8);
        load_lds16(Wft + (size_t)row * CPK + c * 32 + gc * 8, Bb + (size_t)tid * 8);
        asm volatile("s_waitcnt vmcnt(0)" ::: "memory");
        __syncthreads();
        bf16x8 a = *reinterpret_cast<const bf16x8*>(&Ab[(wv * 16 + mm) * 32 + quad * 8]);
#pragma unroll
        for (int t = 0; t < 4; ++t) {
            bf16x8 b = *reinterpret_cast<const bf16x8*>(&Bb[(t * 16 + mm) * 32 + quad * 8]);
            acc[t] = __builtin_amdgcn_mfma_f32_16x16x32_bf16(a, b, acc[t], 0, 0, 0);
        }
        __syncthreads();
    }
    int rbase = m0 + wv * 16 + quad * 4;
#pragma unroll
    for (int t = 0; t < 4; ++t)
#pragma unroll
        for (int r = 0; r < 4; ++r)
            Sbuf[(size_t)(rbase + r) * 64 + t * 16 + mm] = acc[t][r];
}

// ---------------- fp32 GEMM with fused BN on A (score GEMM for small-K layers) ----
__global__ __launch_bounds__(256) void gemm_bn(const float* __restrict__ X,
                                               const float* __restrict__ W,
                                               const float* __restrict__ scale,
                                               const float* __restrict__ shift,
                                               int Cin, int HC, float* __restrict__ OUT) {
    __shared__ float As[8][64];
    __shared__ float Bs[8][64];
    int tid = threadIdx.x;
    int n0 = blockIdx.y * 64;
    int j0 = blockIdx.x * 64;
    int tr = tid >> 4, tc = tid & 15;
    float acc[4][4] = {};
    for (int k0 = 0; k0 < Cin; k0 += 8) {
        int idx = tid;
#pragma unroll
        for (int it = 0; it < 2; ++it, idx += 256) {
            int row = idx >> 3, kk = idx & 7;
            int k = k0 + kk;
            float v = 0.f;
            if (k < Cin) v = scale[k] * X[(size_t)(n0 + row) * Cin + k] + shift[k];
            As[kk][row] = v;
        }
        int idx2 = tid;
#pragma unroll
        for (int it = 0; it < 2; ++it, idx2 += 256) {
            int col = idx2 & 63, kr = idx2 >> 6;
            int k = k0 + kr, j = j0 + col;
            float v = 0.f;
            if (k < Cin && j < HC) v = W[(size_t)k * HC + j];
            Bs[kr][col] = v;
        }
        __syncthreads();
#pragma unroll
        for (int kk = 0; kk < 8; ++kk) {
            float a[4], b[4];
#pragma unroll
            for (int i = 0; i < 4; ++i) a[i] = As[kk][tr * 4 + i];
#pragma unroll
            for (int j = 0; j < 4; ++j) b[j] = Bs[kk][tc * 4 + j];
#pragma unroll
            for (int i = 0; i < 4; ++i)
#pragma unroll
                for (int j = 0; j < 4; ++j) acc[i][j] += a[i] * b[j];
        }
        __syncthreads();
    }
#pragma unroll
    for (int i = 0; i < 4; ++i) {
        int row = n0 + tr * 4 + i;
#pragma unroll
        for (int j = 0; j < 4; ++j) {
            int col = j0 + tc * 4 + j;
            if (col < HC) OUT[(size_t)row * HC + col] = acc[i][j];
        }
    }
}

// ---------------- CSR build (hierarchical 3-pass scan) ----------------
__global__ void count_kernel(const int* __restrict__ dst, int* __restrict__ deg) {
    int e = blockIdx.x * blockDim.x + threadIdx.x;
    if (e < NE) atomicAdd(&deg[dst[e]], 1);
}
__global__ void scan_pass1(const int* __restrict__ deg, int* __restrict__ bsum) {
    __shared__ int red[256];
    int b = blockIdx.x, t = threadIdx.x;
    int lo = b * SCHUNK, hi = min(lo + SCHUNK, NN);
    int s = 0;
    for (int i = lo + t; i < hi; i += 256) s += deg[i] + 1;   // +1 self-loop
    red[t] = s;
    __syncthreads();
    for (int off = 128; off > 0; off >>= 1) {
        if (t < off) red[t] += red[t + off];
        __syncthreads();
    }
    if (t == 0) bsum[b] = red[0];
}
__global__ void scan_pass2(const int* __restrict__ bsum, int* __restrict__ boff,
                           int* __restrict__ rowptr) {
    __shared__ int lds[256];
    int t = threadIdx.x;
    int v0 = bsum[t];
    lds[t] = v0;
    __syncthreads();
    for (int off = 1; off < 256; off <<= 1) {
        int v = (t >= off) ? lds[t - off] : 0;
        __syncthreads();
        lds[t] += v;
        __syncthreads();
    }
    boff[t] = lds[t] - v0;          // exclusive
    if (t == 255) rowptr[NN] = lds[255];
}
__global__ void scan_pass3(const int* __restrict__ deg, const int* __restrict__ boff,
                           int* __restrict__ rowptr, int* __restrict__ cursor) {
    __shared__ int lds[256];
    int b = blockIdx.x, t = threadIdx.x;
    int i = b * SCHUNK + t;
    int d = (t < SCHUNK && i < NN) ? (deg[i] + 1) : 0;   // +1 self-loop
    lds[t] = d;
    __syncthreads();
    for (int off = 1; off < 256; off <<= 1) {
        int v = (t >= off) ? lds[t - off] : 0;
        __syncthreads();
        lds[t] += v;
        __syncthreads();
    }
    if (t < SCHUNK && i < NN) {
        int excl = lds[t] - d + boff[b];
        rowptr[i] = excl;
        cursor[i] = excl;
    }
}
__global__ void scatter_all(const int* __restrict__ src, const int* __restrict__ dst,
                            int* __restrict__ cursor, int* __restrict__ colsrc) {
    int e = blockIdx.x * blockDim.x + threadIdx.x;
    if (e < NE) {
        int pos = atomicAdd(&cursor[dst[e]], 1);
        colsrc[pos] = src[e];
    } else if (e < NE + NN) {
        int n = e - NE;
        int pos = atomicAdd(&cursor[n], 1);
        colsrc[pos] = n;
    }
}

// ---------------- pass A: softmax-aggregate xbn -> z[n, 32*CP] (bf16) ----------------
// Proven r21 form (block-per-node, CH=16, direct uint2 stores, conflicts 0).
template <int CIN, int CP>
__global__ __launch_bounds__(256) void agg_x(const unsigned short* __restrict__ xbn,
                                             const float* __restrict__ S,
                                             const int* __restrict__ rowptr,
                                             const int* __restrict__ colsrc,
                                             int n0, unsigned short* __restrict__ z) {
    constexpr int BS = 256, CH = 16, J = CP / 8;   // J = 16,12,6,2
    constexpr bool V4 = (J % 4 == 0);
    constexpr int NACC = V4 ? (J / 4) : (J / 2);
    constexpr int LIT = CH * 32 / 256;             // 2 logit iterations
    __shared__ __align__(16) float x_lds[CH * CP];
    __shared__ float w_lds[CH * 32];
    __shared__ int cs_lds[CH];
    __shared__ float red_m[8][32];
    __shared__ float red_s[8][32];

    int n = n0 + blockIdx.x;
    int tid = threadIdx.x;
    int start = rowptr[n], end = rowptr[n + 1];
    const int h = tid & 31, g = tid >> 5;
    const int cbase = g * J;
    const float sd = S[(size_t)n * 64 + 32 + h];   // broadcast within head column

    float m_reg = -INFINITY, d_reg = 0.f;
    f32x4 acc4[V4 ? NACC : 1];
    floatx2 acc2[V4 ? 1 : NACC];
    if constexpr (V4) {
#pragma unroll
        for (int j = 0; j < NACC; ++j) acc4[j] = f32x4{0.f, 0.f, 0.f, 0.f};
    } else {
#pragma unroll
        for (int j = 0; j < NACC; ++j) acc2[j] = floatx2{0.f, 0.f};
    }

    for (int chunk = start; chunk < end; chunk += CH) {
        int ce = min(CH, end - chunk);
        int ce32 = ce * 32;
        if (tid < CH && tid < ce) cs_lds[tid] = colsrc[chunk + tid];
        __syncthreads();   // B1: cs_lds visible

        float lreg[LIT];
        float pmx = -INFINITY;
#pragma unroll
        for (int p = 0; p < LIT; ++p) {
            int idx = p * 256 + tid;
            lreg[p] = -INFINITY;
            if (idx < ce32) {
                int e = idx >> 5;
                float l = S[(size_t)cs_lds[e] * 64 + h] + sd;
                l = l > 0.f ? l : 0.2f * l;
                lreg[p] = l;
                pmx = fmaxf(pmx, l);
            }
        }
        red_m[g][h] = pmx;
        // stage x rows (bf16 -> f32) via uint2, f32x4 stores
        for (int idx = tid; idx < ce * (CP / 4); idx += BS) {
            int e = idx / (CP / 4), c4 = idx % (CP / 4);
            uint2 u = reinterpret_cast<const uint2*>(xbn)[(size_t)cs_lds[e] * (CP / 4) + c4];
            f32x4 t;
            t[0] = __uint_as_float(u.x << 16);
            t[1] = __uint_as_float(u.x & 0xFFFF0000u);
            t[2] = __uint_as_float(u.y << 16);
            t[3] = __uint_as_float(u.y & 0xFFFF0000u);
            *reinterpret_cast<f32x4*>(&x_lds[e * CP + 4 * c4]) = t;
        }
        __syncthreads();   // B2: red_m + x_lds visible

        // per-thread redundant max reduce (identical order to serial version)
        float cm = red_m[0][h];
#pragma unroll
        for (int s2 = 1; s2 < 8; ++s2) cm = fmaxf(cm, red_m[s2][h]);
        float newm = fmaxf(m_reg, cm);
        float r = (m_reg == -INFINITY) ? 0.f : __expf(m_reg - newm);
        m_reg = newm;

        float ps = 0.f;
#pragma unroll
        for (int p = 0; p < LIT; ++p) {
            int idx = p * 256 + tid;
            if (idx < ce32) {
                float v = __expf(lreg[p] - m_reg);
                w_lds[idx] = v;
                ps += v;
            }
        }
        red_s[g][h] = ps;
        __syncthreads();   // B3: w_lds + red_s visible

        float ss = red_s[0][h];
#pragma unroll
        for (int s2 = 1; s2 < 8; ++s2) ss += red_s[s2][h];
        d_reg = d_reg * r + ss;

        if constexpr (V4) {
            f32x4 rr4 = {r, r, r, r};
#pragma unroll
            for (int j = 0; j < NACC; ++j) acc4[j] *= rr4;
            for (int e = 0; e < ce; ++e) {
                float w = w_lds[e * 32 + h];
                f32x4 w4 = {w, w, w, w};
                const f32x4* xv = reinterpret_cast<const f32x4*>(&x_lds[e * CP + cbase]);
#pragma unroll
                for (int j = 0; j < NACC; ++j) acc4[j] += w4 * xv[j];
            }
        } else {
            floatx2 rr2 = {r, r};
#pragma unroll
            for (int j = 0; j < NACC; ++j) acc2[j] *= rr2;
            for (int e = 0; e < ce; ++e) {
                float w = w_lds[e * 32 + h];
                floatx2 w2 = {w, w};
                const floatx2* xv = reinterpret_cast<const floatx2*>(&x_lds[e * CP + cbase]);
#pragma unroll
                for (int j = 0; j < NACC; ++j) acc2[j] += w2 * xv[j];
            }
        }
    }

    float dinv = 1.f / d_reg;
    if constexpr (V4) {
        uint2* zp = reinterpret_cast<uint2*>(
            z + (size_t)(n - n0) * (32 * CP) + h * CP + cbase);
#pragma unroll
        for (int j = 0; j < NACC; ++j) {
            uint2 t;
            t.x = cvt_pk_bf16(acc4[j][0] * dinv, acc4[j][1] * dinv);
            t.y = cvt_pk_bf16(acc4[j][2] * dinv, acc4[j][3] * dinv);
            zp[j] = t;
        }
    } else {
        unsigned int* zp = reinterpret_cast<unsigned int*>(
            z + (size_t)(n - n0) * (32 * CP) + h * CP + cbase);
#pragma unroll
        for (int j = 0; j < NACC; ++j)
            zp[j] = cvt_pk_bf16(acc2[j][0] * dinv, acc2[j][1] * dinv);
    }
}

// ---------------- pass B: LDS-tiled MFMA GEMM (MT=64) ----------------
// r25: runtime nr (row count) for single-slab layers; FB path optionally emits
// per-channel BN stat partials (NT==1 layers) via a deterministic LDS tree.
template <int NT, int KP, int KS, bool FB, bool STATS>
__global__ __launch_bounds__(256) void gemm_z_t(const unsigned short* __restrict__ z,
                                                const unsigned short* __restrict__ Wt,
                                                float* __restrict__ obuf,
                                                const float* __restrict__ bias,
                                                int n0, int COUT, int nr,
                                                float* __restrict__ statp) {
    constexpr int NP = NT * 16;
    constexpr int KSEG = KP / KS;       // multiple of 64
    constexpr int NC = KSEG / 64;
    constexpr int MT = 64;
    __shared__ unsigned short Abuf[2][MT * 64];
    __shared__ unsigned short Bbuf[2][NP * 64];

    const int m0 = blockIdx.x * MT;
    const int kbeg = blockIdx.y * KSEG;
    const int tid = threadIdx.x;
    const int wv = tid >> 6;
    const int lane = tid & 63;
    const int mm = lane & 15, quad = lane >> 4;

    auto stage = [&](int buf, int kk) {
#pragma unroll
        for (int it = 0; it < 2; ++it) {
            int gi = it * 256 + tid;
            int row = gi >> 3, gc = gi & 7;
            int srow = m0 + row;
            if (srow > nr - 1) srow = nr - 1;
            const unsigned short* src = z + (size_t)srow * KP + kk + gc * 8;
            unsigned short* dst = &Abuf[buf][(size_t)(it * 256 + wv * 64) * 8];
            load_lds16(src, dst);
        }
#pragma unroll
        for (int it = 0; it < (NP * 8 + 255) / 256; ++it) {
            int gi = it * 256 + tid;
            if (gi < NP * 8) {
                int row = gi >> 3, gc = gi & 7;
                const unsigned short* src = Wt + (size_t)row * KP + kk + gc * 8;
                unsigned short* dst = &Bbuf[buf][(size_t)(it * 256 + wv * 64) * 8];
                load_lds16(src, dst);
            }
        }
    };

    f32x4 acc[NT];
#pragma unroll
    for (int t = 0; t < NT; ++t) acc[t] = f32x4{0.f, 0.f, 0.f, 0.f};

    stage(0, kbeg);
    for (int c = 0; c < NC; ++c) {
        asm volatile("s_waitcnt vmcnt(0)" ::: "memory");
        __syncthreads();
        int cur = c & 1;
        if (c + 1 < NC) stage(cur ^ 1, kbeg + (c + 1) * 64);
        const unsigned short* Ab = Abuf[cur];
        const unsigned short* Bb = Bbuf[cur];
#pragma unroll
        for (int hh = 0; hh < 2; ++hh) {
            bf16x8 a0 = *reinterpret_cast<const bf16x8*>(&Ab[(wv * 16 + mm) * 64 + hh * 32 + quad * 8]);
#pragma unroll
            for (int t = 0; t < NT; ++t) {
                bf16x8 b = *reinterpret_cast<const bf16x8*>(&Bb[(t * 16 + mm) * 64 + hh * 32 + quad * 8]);
                acc[t] = __builtin_amdgcn_mfma_f32_16x16x32_bf16(a0, b, acc[t], 0, 0, 0);
            }
        }
        __syncthreads();
    }

    int row0 = quad * 4;
    if constexpr (FB) {
        float s = 0.f, q = 0.f;
#pragma unroll
        for (int t = 0; t < NT; ++t) {
            int cc = t * 16 + mm;
#pragma unroll
            for (int r = 0; r < 4; ++r) {
                int m = m0 + wv * 16 + row0 + r;
                if (m < nr && cc < COUT) {
                    float v = acc[t][r] + bias[cc];
                    v = v > 0.f ? v : 0.01f * v;
                    obuf[(size_t)(n0 + m) * COUT + cc] = v;
                    if constexpr (STATS) { s += v; q += v * v; }
                }
            }
        }
        if constexpr (STATS) {
            static_assert(NT == 1, "STATS path assumes NT==1");
            __shared__ float ssum[4][4][16], sqsum[4][4][16];
            ssum[wv][quad][mm] = s; sqsum[wv][quad][mm] = q;
            __syncthreads();
            if (tid < 16) {
                float S = 0.f, Q = 0.f;
#pragma unroll
                for (int a = 0; a < 4; ++a)
#pragma unroll
                    for (int b2 = 0; b2 < 4; ++b2) {
                        S += ssum[a][b2][tid]; Q += sqsum[a][b2][tid];
                    }
                if (tid < COUT) {
                    statp[(size_t)blockIdx.x * 2 * COUT + tid] = S;
                    statp[(size_t)blockIdx.x * 2 * COUT + COUT + tid] = Q;
                }
            }
        }
    } else {
        float* pb = obuf + (size_t)blockIdx.y * MPAD * NP;
#pragma unroll
        for (int t = 0; t < NT; ++t) {
            int cc = t * 16 + mm;
#pragma unroll
            for (int r = 0; r < 4; ++r) {
                int m = m0 + wv * 16 + row0 + r;
                pb[(size_t)m * NP + cc] = acc[t][r];
            }
        }
    }
}

// reduce K-split partials + bias + leaky 0.01 -> xout, AND emit per-channel BN
// stat partials for the NEXT layer (r25). blockDim = NPAD (one channel/thread);
// grid-stride over rows => deterministic per-channel sum order.
template <int NPAD>
__global__ void reduce_parts_stats(const float* __restrict__ pbuf, int KS, int COUT,
                                   const float* __restrict__ bias, int n0, int slab,
                                   float* __restrict__ xout, float* __restrict__ statp) {
    const int c = threadIdx.x;       // [0, NPAD)
    const bool act = (c < COUT);
    const float bv = act ? bias[c] : 0.f;
    float s = 0.f, q = 0.f;
    for (int m = blockIdx.x; m < NSLAB; m += gridDim.x) {
        float t = 0.f;
        for (int p = 0; p < KS; ++p)
            t += pbuf[(size_t)p * MPAD * NPAD + (size_t)m * NPAD + c];
        if (act) {
            float v = t + bv;
            v = v > 0.f ? v : 0.01f * v;
            xout[(size_t)(n0 + m) * COUT + c] = v;
            s += v; q += v * v;
        }
    }
    if (act) {
        int b = slab * gridDim.x + blockIdx.x;
        statp[(size_t)b * 2 * COUT + c] = s;
        statp[(size_t)b * 2 * COUT + COUT + c] = q;
    }
}

// ---------------- fused mean-pool + FC + sigmoid ----------------
__global__ __launch_bounds__(64) void pool_head(const float* __restrict__ x4,
                                                const int* __restrict__ batch,
                                                const float* __restrict__ cond,
                                                const float* __restrict__ fcW,
                                                const float* __restrict__ fcb,
                                                float* __restrict__ out) {
    int g = blockIdx.x;
    int lane = threadIdx.x;
    int lo = 0, hi = NN;
    while (lo < hi) { int mid = (lo + hi) >> 1; if (batch[mid] < g) lo = mid + 1; else hi = mid; }
    int lo2 = lo, hi2 = NN;
    while (lo2 < hi2) { int mid = (lo2 + hi2) >> 1; if (batch[mid] < g + 1) lo2 = mid + 1; else hi2 = mid; }
    int beg = lo, end = lo2;

    float s[5] = {0.f, 0.f, 0.f, 0.f, 0.f};
    for (int n = beg + lane; n < end; n += 64) {
#pragma unroll
        for (int c = 0; c < 5; ++c) s[c] += x4[(size_t)n * 5 + c];
    }
    float cz = 0.f;
    if (lane < 100) cz = cond[lane] * fcW[5 + lane];
    if (lane + 64 < 100) cz += cond[lane + 64] * fcW[5 + lane + 64];
#pragma unroll
    for (int off = 32; off > 0; off >>= 1) {
#pragma unroll
        for (int c = 0; c < 5; ++c) s[c] += __shfl_down(s[c], off, 64);
        cz += __shfl_down(cz, off, 64);
    }
    if (lane == 0) {
        float cnt = fmaxf((float)(end - beg), 1.f);
        float zv = fcb[0] + cz;
#pragma unroll
        for (int c = 0; c < 5; ++c) zv += (s[c] / cnt) * fcW[c];
        out[g] = 1.f / (1.f + __expf(-zv));
    }
}

// ---------------- per-layer driver ----------------
struct LayerBufs {
    float* scale; float* shift;
    unsigned short* xbn; unsigned short* zbuf;
    float* Sbuf; float* pbuf; const int* rowptr; const int* colsrc;
};

// sp_in/nb_in: BN stat partials for THIS layer's input ([b][2][CIN], nb entries).
// statp: where this layer's epilogue writes stat partials for the NEXT layer.
template <int CIN, int CP, int COUT, int NP, int NT, int KS, int SLABS, bool OSTATS>
static void run_layer(const float* xin, const float* sp_in, int nb_in,
                      const float* Wf, const unsigned short* Wft,
                      const unsigned short* Wt,
                      const float* Bv, const float* G, const float* Be,
                      float* xout, float* statp, const LayerBufs& B, hipStream_t stream) {
    constexpr int KP = 32 * CP;
    constexpr int NPAD = NT * 16;
    constexpr int NR = NN / SLABS;
    bn_apply_f<CIN, CP><<<512, 256, 0, stream>>>(xin, sp_in, nb_in, G, Be,
                                                 B.scale, B.shift, B.xbn);
    if constexpr (CP >= 64) {
        gemm_s<CP><<<NN / 64, 256, 0, stream>>>(B.xbn, Wft, B.Sbuf);
    } else {
        gemm_bn<<<dim3(1, NN / 64), 256, 0, stream>>>(xin, Wf, B.scale, B.shift, CIN, 64, B.Sbuf);
    }
    for (int s = 0; s < SLABS; ++s) {
        int n0 = s * NR;
        agg_x<CIN, CP><<<NR, 256, 0, stream>>>(B.xbn, B.Sbuf, B.rowptr, B.colsrc, n0, B.zbuf);
        if constexpr (KS > 1) {
            static_assert(SLABS == 2, "K-split path assumes NSLAB rows");
            gemm_z_t<NT, KP, KS, false, false><<<dim3(MPAD / 64, KS), 256, 0, stream>>>(
                B.zbuf, Wt, B.pbuf, nullptr, n0, COUT, NR, nullptr);
            reduce_parts_stats<NPAD><<<256, NPAD, 0, stream>>>(
                B.pbuf, KS, COUT, Bv, n0, s, xout, statp);
        } else {
            gemm_z_t<NT, KP, 1, true, OSTATS><<<dim3((NR + 63) / 64, 1), 256, 0, stream>>>(
                B.zbuf, Wt, xout, Bv, n0, COUT, NR, statp);
        }
    }
}

extern "C" void kernel_launch(void* const* d_in, const int* in_sizes, int n_in,
                              void* d_out, int out_size, void* d_ws, size_t ws_size,
                              hipStream_t stream) {
    (void)in_sizes; (void)n_in; (void)out_size;
    const float* x     = (const float*)d_in[0];
    const int*   ei    = (const int*)d_in[1];
    const int*   batch = (const int*)d_in[2];
    const float* cond  = (const float*)d_in[3];
    const float* W[4]  = {(const float*)d_in[4],  (const float*)d_in[8],
                          (const float*)d_in[12], (const float*)d_in[16]};
    const float* Asp[4] = {(const float*)d_in[5],  (const float*)d_in[9],
                           (const float*)d_in[13], (const float*)d_in[17]};
    const float* Adp[4] = {(const float*)d_in[6],  (const float*)d_in[10],
                           (const float*)d_in[14], (const float*)d_in[18]};
    const float* Bv[4]  = {(const float*)d_in[7],  (const float*)d_in[11],
                           (const float*)d_in[15], (const float*)d_in[19]};
    const float* G[4]   = {(const float*)d_in[20], (const float*)d_in[22],
                           (const float*)d_in[24], (const float*)d_in[26]};
    const float* Be[4]  = {(const float*)d_in[21], (const float*)d_in[23],
                           (const float*)d_in[25], (const float*)d_in[27]};
    const float* fcW = (const float*)d_in[30];
    const float* fcb = (const float*)d_in[31];
    float* out = (float*)d_out;

    char* base = (char*)d_ws;
    size_t off = 0;
    auto alloc = [&](size_t b) {
        size_t o = off;
        off += (b + 255) & ~(size_t)255;
        return (void*)(base + o);
    };
    unsigned short* zbuf = (unsigned short*)alloc((size_t)NSLAB * 4096 * 2);
    unsigned short* xbn  = (unsigned short*)alloc((size_t)NN * 128 * 2);
    float* pbuf    = (float*)alloc((size_t)4 * MPAD * 96 * 4);
    float* xbuf    = (float*)alloc((size_t)NN * 90 * 4);
    float* Sbuf    = (float*)alloc((size_t)NN * 64 * 4);
    float* partial = (float*)alloc((size_t)NPB * 2 * 128 * 4);
    float* stat1   = (float*)alloc((size_t)NPB * 2 * 128 * 4);
    float* scale   = (float*)alloc(128 * 4);
    float* shift   = (float*)alloc(128 * 4);
    // per-layer weight buffers (prep hoisted to one upfront dispatch)
    const int CPs[4]  = {128, 96, 48, 16};
    const int NPs[4]  = {96, 48, 16, 16};
    const int CINs[4] = {128, 90, 45, 15};
    const int COUTs[4] = {90, 45, 15, 5};
    float* Wf_a[4]; unsigned short* Wft_a[4]; unsigned short* Wt_a[4];
    for (int i = 0; i < 4; ++i) {
        Wf_a[i]  = (float*)alloc((size_t)CPs[i] * 64 * 4);
        Wft_a[i] = (unsigned short*)alloc((size_t)64 * CPs[i] * 2);
        Wt_a[i]  = (unsigned short*)alloc((size_t)NPs[i] * 32 * CPs[i] * 2);
    }
    int* deg     = (int*)alloc((size_t)NN * 4);
    int* rowptr  = (int*)alloc((size_t)(NN + 1) * 4);
    int* cursor  = (int*)alloc((size_t)NN * 4);
    int* colsrc  = (int*)alloc((size_t)(NE + NN) * 4);
    int* bsum    = (int*)alloc((size_t)SCB * 4);
    int* boff    = (int*)alloc((size_t)SCB * 4);
    if (off > ws_size) return;

    const int* srcp = ei;
    const int* dstp = ei + NE;

    // all-layer weight prep in one dispatch, first (independent of everything)
    PrepArgs PA;
    int bb = 0;
    for (int i = 0; i < 4; ++i) {
        PA.L[i] = PrepLayer{W[i], Asp[i], Adp[i], Wf_a[i], Wft_a[i], Wt_a[i],
                            CINs[i], CPs[i], COUTs[i], NPs[i], bb};
        bb += CPs[i] + NPs[i];
    }
    PA.nb = bb;
    prep_all<<<bb, 256, 0, stream>>>(PA);

    // CSR by dst (hierarchical scan); deg zeroed via memset, self-loop +1 in scans
    hipMemsetAsync(deg, 0, (size_t)NN * 4, stream);
    count_kernel<<<(NE + 255) / 256, 256, 0, stream>>>(dstp, deg);
    scan_pass1<<<SCB, 256, 0, stream>>>(deg, bsum);
    scan_pass2<<<1, 256, 0, stream>>>(bsum, boff, rowptr);
    scan_pass3<<<SCB, 256, 0, stream>>>(deg, boff, rowptr, cursor);
    scatter_all<<<(NE + NN + 255) / 256, 256, 0, stream>>>(srcp, dstp, cursor, colsrc);

    LayerBufs B{scale, shift, xbn, zbuf, Sbuf, pbuf, rowptr, colsrc};

    // L1 input stats from raw x; L2-L4 stats flow from the previous epilogue.
    bn_partial<<<NPB, 128, 0, stream>>>(x, NN, 128, partial);

    // L1: 128->90 (2 slabs, KS=4; reduce emits stats->stat1, nb=512)
    run_layer<128, 128, 90, 96, 6, 4, 2, false>(x, partial, NPB,
        Wf_a[0], Wft_a[0], Wt_a[0], Bv[0], G[0], Be[0], xbuf, stat1, B, stream);
    // L2: 90->45 (2 slabs, KS=3; reduce emits stats->partial, nb=512)
    run_layer< 90,  96, 45, 48, 3, 3, 2, false>(xbuf, stat1, 512,
        Wf_a[1], Wft_a[1], Wt_a[1], Bv[1], G[1], Be[1], xbuf, partial, B, stream);
    // L3: 45->15 (single slab, FB gemm emits stats->stat1, nb=625)
    run_layer< 45,  48, 15, 16, 1, 1, 1, true >(xbuf, partial, 512,
        Wf_a[2], Wft_a[2], Wt_a[2], Bv[2], G[2], Be[2], xbuf, stat1, B, stream);
    // L4: 15->5 (single slab, no downstream BN)
    run_layer< 15,  16,  5, 16, 1, 1, 1, false>(xbuf, stat1, 625,
        Wf_a[3], Wft_a[3], Wt_a[3], Bv[3], G[3], Be[3], xbuf, stat1, B, stream);

    pool_head<<<256, 64, 0, stream>>>(xbuf, batch, cond, fcW, fcb, out);
}

// Round 11
// 1189.687 us; speedup vs baseline: 1.2122x; 1.2122x over previous
//
#include <hip/hip_runtime.h>
#include <hip/hip_bf16.h>

// ---------------- constants ----------------
constexpr int NN = 40000;   // nodes
constexpr int NE = 400000;  // edges (before self-loops)
constexpr int NSLAB = 20000;
constexpr int MPAD = 20096; // 157 * 128 (M-tile overrun padding; 314 * 64)
constexpr int SCB = 256;    // scan blocks
constexpr int SCHUNK = (NN + SCB - 1) / SCB;   // 157 (<= 256)
constexpr int NPB = 512;    // bn_partial blocks (rows of `partial`)

__device__ __forceinline__ unsigned short f2bf(float f) {
    unsigned int u = __float_as_uint(f);
    unsigned int r = (u + 0x7FFFu + ((u >> 16) & 1u)) >> 16;
    return (unsigned short)r;
}

// packed f32x2 -> bf16x2, RTNE (bit-identical to f2bf pairs), 1 instruction
__device__ __forceinline__ unsigned int cvt_pk_bf16(float a, float b) {
    unsigned int r;
    asm("v_cvt_pk_bf16_f32 %0, %1, %2" : "=v"(r) : "v"(a), "v"(b));
    return r;
}

// async global->LDS 16B: no VGPR round-trip, loads issue back-to-back.
__device__ __forceinline__ void load_lds16(const unsigned short* g, unsigned short* l) {
    __builtin_amdgcn_global_load_lds(
        (const __attribute__((address_space(1))) unsigned int*)(g),
        (__attribute__((address_space(3))) unsigned int*)(l), 16, 0, 0);
}

typedef __attribute__((ext_vector_type(8))) short bf16x8;
typedef __attribute__((ext_vector_type(4))) float f32x4;
typedef __attribute__((ext_vector_type(2))) float floatx2;

// ---------------- BN ----------------
// Input stats for L1 (raw x), L2, L3 (prev outputs). L4's stats come from L3's
// FB-gemm epilogue (r26: r25's reduce_parts_stats reverted — it serialized to
// 24K threads / 254 GB/s, 91.5us x4; the FB STATS path is kept, it was cheap).
__global__ void bn_partial(const float* __restrict__ x, int N, int C,
                           float* __restrict__ partial) {
    int ch = threadIdx.x;            // blockDim = 128, C <= 128
    if (ch >= C) return;
    float s = 0.f, sq = 0.f;
    for (int n = blockIdx.x; n < N; n += gridDim.x) {
        float v = x[(size_t)n * C + ch];
        s += v; sq += v * v;
    }
    partial[(size_t)blockIdx.x * 2 * C + ch]     = s;
    partial[(size_t)blockIdx.x * 2 * C + C + ch] = sq;
}

// fused finalize + apply: every block derives scale/shift from `partial`
// (nb entries of layout [b][2][CIN], runtime nb; two half-sums), block 0
// publishes for gemm_bn; then grid-stride packed bf16 apply.
template <int CIN, int CP>
__global__ __launch_bounds__(256) void bn_apply_f(const float* __restrict__ x,
                                                  const float* __restrict__ partial,
                                                  int nb,
                                                  const float* __restrict__ g,
                                                  const float* __restrict__ be,
                                                  float* __restrict__ scale_g,
                                                  float* __restrict__ shift_g,
                                                  unsigned short* __restrict__ xbn) {
    __shared__ float hs[2][128], hq[2][128];
    __shared__ float sc_l[CP], sh_l[CP];
    const int tid = threadIdx.x;
    const int half = tid >> 7, ch = tid & 127;
    if (ch < CIN) {
        int b0 = half ? (nb >> 1) : 0;
        int b1 = half ? nb : (nb >> 1);
        float s = 0.f, sq = 0.f;
        for (int b = b0; b < b1; ++b) {
            s  += partial[(size_t)b * 2 * CIN + ch];
            sq += partial[(size_t)b * 2 * CIN + CIN + ch];
        }
        hs[half][ch] = s; hq[half][ch] = sq;
    }
    __syncthreads();
    if (tid < CP) {
        float sc = 0.f, sh = 0.f;
        if (tid < CIN) {
            float s  = hs[0][tid] + hs[1][tid];
            float sq = hq[0][tid] + hq[1][tid];
            float mean = s / (float)NN;
            float var  = sq / (float)NN - mean * mean;
            float inv  = rsqrtf(var + 1e-5f);
            sc = g[tid] * inv;
            sh = be[tid] - mean * sc;
            if (blockIdx.x == 0) { scale_g[tid] = sc; shift_g[tid] = sh; }
        }
        sc_l[tid] = sc; sh_l[tid] = sh;
    }
    __syncthreads();
    const int total = NN * (CP / 2);
    for (int idx = blockIdx.x * 256 + tid; idx < total; idx += 256 * gridDim.x) {
        int n = idx / (CP / 2), c2 = idx % (CP / 2);
        int c = 2 * c2;
        float v0 = 0.f, v1 = 0.f;
        if (c < CIN)     v0 = sc_l[c] * x[(size_t)n * CIN + c] + sh_l[c];
        if (c + 1 < CIN) v1 = sc_l[c + 1] * x[(size_t)n * CIN + c + 1] + sh_l[c + 1];
        reinterpret_cast<unsigned int*>(xbn)[idx] = cvt_pk_bf16(v0, v1);
    }
}

// ---------------- fused weight prep for ALL layers in ONE dispatch (r20) ----------
struct PrepLayer {
    const float* W; const float* as_; const float* ad_;
    float* Wf; unsigned short* Wft; unsigned short* Wt;
    int CIN, CP, COUT, NP, bbase;
};
struct PrepArgs { PrepLayer L[4]; int nb; };

__global__ void prep_all(PrepArgs A) {
    int bid = blockIdx.x;
    int li = 0;
#pragma unroll
    for (int i = 1; i < 4; ++i)
        if (bid >= A.L[i].bbase) li = i;
    const PrepLayer& P = A.L[li];
    const int CIN = P.CIN, CP = P.CP, COUT = P.COUT;
    int b = bid - P.bbase;
    int tid = threadIdx.x;
    if (b < CP) {
        int cin = b;
        if (tid < 64) {
            int j = tid, h = j & 31;
            float s = 0.f;
            if (cin < CIN) {
                const float* a = (j < 32) ? P.as_ : P.ad_;
                const float* wrow = P.W + (size_t)cin * 32 * COUT + (size_t)h * COUT;
                const float* arow = a + (size_t)h * COUT;
                for (int c = 0; c < COUT; ++c) s += wrow[c] * arow[c];
            }
            P.Wf[cin * 64 + j] = s;
            P.Wft[j * CP + cin] = f2bf(s);
        }
    } else {
        int c = b - CP;   // [0, NP)
        for (int kk = tid; kk < 32 * CP; kk += blockDim.x) {
            int h = kk / CP, k = kk % CP;
            float v = 0.f;
            if (k < CIN && c < COUT)
                v = P.W[(size_t)k * (32 * COUT) + h * COUT + c] * (1.f / 32.f);
            P.Wt[(size_t)c * (32 * CP) + kk] = f2bf(v);
        }
    }
}

// ---------------- MFMA score GEMM: Sbuf[n, 0:64] = xbn[n,:] @ Wft^T ------------------
template <int CPK>
__global__ __launch_bounds__(256) void gemm_s(const unsigned short* __restrict__ xbn,
                                              const unsigned short* __restrict__ Wft,
                                              float* __restrict__ Sbuf) {
    constexpr int NC = CPK / 32;
    __shared__ unsigned short Ab[64 * 32];
    __shared__ unsigned short Bb[64 * 32];
    const int m0 = blockIdx.x * 64;
    const int tid = threadIdx.x;
    const int wv = tid >> 6, lane = tid & 63;
    const int mm = lane & 15, quad = lane >> 4;
    f32x4 acc[4];
#pragma unroll
    for (int t = 0; t < 4; ++t) acc[t] = f32x4{0.f, 0.f, 0.f, 0.f};

    for (int c = 0; c < NC; ++c) {
        int row = tid >> 2, gc = tid & 3;
        load_lds16(xbn + (size_t)(m0 + row) * CPK + c * 32 + gc * 8, Ab + (size_t)tid * 8);
        load_lds16(Wft + (size_t)row * CPK + c * 32 + gc * 8, Bb + (size_t)tid * 8);
        asm volatile("s_waitcnt vmcnt(0)" ::: "memory");
        __syncthreads();
        bf16x8 a = *reinterpret_cast<const bf16x8*>(&Ab[(wv * 16 + mm) * 32 + quad * 8]);
#pragma unroll
        for (int t = 0; t < 4; ++t) {
            bf16x8 b = *reinterpret_cast<const bf16x8*>(&Bb[(t * 16 + mm) * 32 + quad * 8]);
            acc[t] = __builtin_amdgcn_mfma_f32_16x16x32_bf16(a, b, acc[t], 0, 0, 0);
        }
        __syncthreads();
    }
    int rbase = m0 + wv * 16 + quad * 4;
#pragma unroll
    for (int t = 0; t < 4; ++t)
#pragma unroll
        for (int r = 0; r < 4; ++r)
            Sbuf[(size_t)(rbase + r) * 64 + t * 16 + mm] = acc[t][r];
}

// ---------------- fp32 GEMM with fused BN on A (score GEMM for small-K layers) ----
__global__ __launch_bounds__(256) void gemm_bn(const float* __restrict__ X,
                                               const float* __restrict__ W,
                                               const float* __restrict__ scale,
                                               const float* __restrict__ shift,
                                               int Cin, int HC, float* __restrict__ OUT) {
    __shared__ float As[8][64];
    __shared__ float Bs[8][64];
    int tid = threadIdx.x;
    int n0 = blockIdx.y * 64;
    int j0 = blockIdx.x * 64;
    int tr = tid >> 4, tc = tid & 15;
    float acc[4][4] = {};
    for (int k0 = 0; k0 < Cin; k0 += 8) {
        int idx = tid;
#pragma unroll
        for (int it = 0; it < 2; ++it, idx += 256) {
            int row = idx >> 3, kk = idx & 7;
            int k = k0 + kk;
            float v = 0.f;
            if (k < Cin) v = scale[k] * X[(size_t)(n0 + row) * Cin + k] + shift[k];
            As[kk][row] = v;
        }
        int idx2 = tid;
#pragma unroll
        for (int it = 0; it < 2; ++it, idx2 += 256) {
            int col = idx2 & 63, kr = idx2 >> 6;
            int k = k0 + kr, j = j0 + col;
            float v = 0.f;
            if (k < Cin && j < HC) v = W[(size_t)k * HC + j];
            Bs[kr][col] = v;
        }
        __syncthreads();
#pragma unroll
        for (int kk = 0; kk < 8; ++kk) {
            float a[4], b[4];
#pragma unroll
            for (int i = 0; i < 4; ++i) a[i] = As[kk][tr * 4 + i];
#pragma unroll
            for (int j = 0; j < 4; ++j) b[j] = Bs[kk][tc * 4 + j];
#pragma unroll
            for (int i = 0; i < 4; ++i)
#pragma unroll
                for (int j = 0; j < 4; ++j) acc[i][j] += a[i] * b[j];
        }
        __syncthreads();
    }
#pragma unroll
    for (int i = 0; i < 4; ++i) {
        int row = n0 + tr * 4 + i;
#pragma unroll
        for (int j = 0; j < 4; ++j) {
            int col = j0 + tc * 4 + j;
            if (col < HC) OUT[(size_t)row * HC + col] = acc[i][j];
        }
    }
}

// ---------------- CSR build (hierarchical 3-pass scan) ----------------
__global__ void count_kernel(const int* __restrict__ dst, int* __restrict__ deg) {
    int e = blockIdx.x * blockDim.x + threadIdx.x;
    if (e < NE) atomicAdd(&deg[dst[e]], 1);
}
__global__ void scan_pass1(const int* __restrict__ deg, int* __restrict__ bsum) {
    __shared__ int red[256];
    int b = blockIdx.x, t = threadIdx.x;
    int lo = b * SCHUNK, hi = min(lo + SCHUNK, NN);
    int s = 0;
    for (int i = lo + t; i < hi; i += 256) s += deg[i] + 1;   // +1 self-loop
    red[t] = s;
    __syncthreads();
    for (int off = 128; off > 0; off >>= 1) {
        if (t < off) red[t] += red[t + off];
        __syncthreads();
    }
    if (t == 0) bsum[b] = red[0];
}
__global__ void scan_pass2(const int* __restrict__ bsum, int* __restrict__ boff,
                           int* __restrict__ rowptr) {
    __shared__ int lds[256];
    int t = threadIdx.x;
    int v0 = bsum[t];
    lds[t] = v0;
    __syncthreads();
    for (int off = 1; off < 256; off <<= 1) {
        int v = (t >= off) ? lds[t - off] : 0;
        __syncthreads();
        lds[t] += v;
        __syncthreads();
    }
    boff[t] = lds[t] - v0;          // exclusive
    if (t == 255) rowptr[NN] = lds[255];
}
__global__ void scan_pass3(const int* __restrict__ deg, const int* __restrict__ boff,
                           int* __restrict__ rowptr, int* __restrict__ cursor) {
    __shared__ int lds[256];
    int b = blockIdx.x, t = threadIdx.x;
    int i = b * SCHUNK + t;
    int d = (t < SCHUNK && i < NN) ? (deg[i] + 1) : 0;   // +1 self-loop
    lds[t] = d;
    __syncthreads();
    for (int off = 1; off < 256; off <<= 1) {
        int v = (t >= off) ? lds[t - off] : 0;
        __syncthreads();
        lds[t] += v;
        __syncthreads();
    }
    if (t < SCHUNK && i < NN) {
        int excl = lds[t] - d + boff[b];
        rowptr[i] = excl;
        cursor[i] = excl;
    }
}
__global__ void scatter_all(const int* __restrict__ src, const int* __restrict__ dst,
                            int* __restrict__ cursor, int* __restrict__ colsrc) {
    int e = blockIdx.x * blockDim.x + threadIdx.x;
    if (e < NE) {
        int pos = atomicAdd(&cursor[dst[e]], 1);
        colsrc[pos] = src[e];
    } else if (e < NE + NN) {
        int n = e - NE;
        int pos = atomicAdd(&cursor[n], 1);
        colsrc[pos] = n;
    }
}

// ---------------- pass A: softmax-aggregate xbn -> z[n, 32*CP] (bf16) ----------------
// Proven r21 form (block-per-node, CH=16, direct uint2 stores, conflicts 0).
template <int CIN, int CP>
__global__ __launch_bounds__(256) void agg_x(const unsigned short* __restrict__ xbn,
                                             const float* __restrict__ S,
                                             const int* __restrict__ rowptr,
                                             const int* __restrict__ colsrc,
                                             int n0, unsigned short* __restrict__ z) {
    constexpr int BS = 256, CH = 16, J = CP / 8;   // J = 16,12,6,2
    constexpr bool V4 = (J % 4 == 0);
    constexpr int NACC = V4 ? (J / 4) : (J / 2);
    constexpr int LIT = CH * 32 / 256;             // 2 logit iterations
    __shared__ __align__(16) float x_lds[CH * CP];
    __shared__ float w_lds[CH * 32];
    __shared__ int cs_lds[CH];
    __shared__ float red_m[8][32];
    __shared__ float red_s[8][32];

    int n = n0 + blockIdx.x;
    int tid = threadIdx.x;
    int start = rowptr[n], end = rowptr[n + 1];
    const int h = tid & 31, g = tid >> 5;
    const int cbase = g * J;
    const float sd = S[(size_t)n * 64 + 32 + h];   // broadcast within head column

    float m_reg = -INFINITY, d_reg = 0.f;
    f32x4 acc4[V4 ? NACC : 1];
    floatx2 acc2[V4 ? 1 : NACC];
    if constexpr (V4) {
#pragma unroll
        for (int j = 0; j < NACC; ++j) acc4[j] = f32x4{0.f, 0.f, 0.f, 0.f};
    } else {
#pragma unroll
        for (int j = 0; j < NACC; ++j) acc2[j] = floatx2{0.f, 0.f};
    }

    for (int chunk = start; chunk < end; chunk += CH) {
        int ce = min(CH, end - chunk);
        int ce32 = ce * 32;
        if (tid < CH && tid < ce) cs_lds[tid] = colsrc[chunk + tid];
        __syncthreads();   // B1: cs_lds visible

        float lreg[LIT];
        float pmx = -INFINITY;
#pragma unroll
        for (int p = 0; p < LIT; ++p) {
            int idx = p * 256 + tid;
            lreg[p] = -INFINITY;
            if (idx < ce32) {
                int e = idx >> 5;
                float l = S[(size_t)cs_lds[e] * 64 + h] + sd;
                l = l > 0.f ? l : 0.2f * l;
                lreg[p] = l;
                pmx = fmaxf(pmx, l);
            }
        }
        red_m[g][h] = pmx;
        // stage x rows (bf16 -> f32) via uint2, f32x4 stores
        for (int idx = tid; idx < ce * (CP / 4); idx += BS) {
            int e = idx / (CP / 4), c4 = idx % (CP / 4);
            uint2 u = reinterpret_cast<const uint2*>(xbn)[(size_t)cs_lds[e] * (CP / 4) + c4];
            f32x4 t;
            t[0] = __uint_as_float(u.x << 16);
            t[1] = __uint_as_float(u.x & 0xFFFF0000u);
            t[2] = __uint_as_float(u.y << 16);
            t[3] = __uint_as_float(u.y & 0xFFFF0000u);
            *reinterpret_cast<f32x4*>(&x_lds[e * CP + 4 * c4]) = t;
        }
        __syncthreads();   // B2: red_m + x_lds visible

        // per-thread redundant max reduce (identical order to serial version)
        float cm = red_m[0][h];
#pragma unroll
        for (int s2 = 1; s2 < 8; ++s2) cm = fmaxf(cm, red_m[s2][h]);
        float newm = fmaxf(m_reg, cm);
        float r = (m_reg == -INFINITY) ? 0.f : __expf(m_reg - newm);
        m_reg = newm;

        float ps = 0.f;
#pragma unroll
        for (int p = 0; p < LIT; ++p) {
            int idx = p * 256 + tid;
            if (idx < ce32) {
                float v = __expf(lreg[p] - m_reg);
                w_lds[idx] = v;
                ps += v;
            }
        }
        red_s[g][h] = ps;
        __syncthreads();   // B3: w_lds + red_s visible

        float ss = red_s[0][h];
#pragma unroll
        for (int s2 = 1; s2 < 8; ++s2) ss += red_s[s2][h];
        d_reg = d_reg * r + ss;

        if constexpr (V4) {
            f32x4 rr4 = {r, r, r, r};
#pragma unroll
            for (int j = 0; j < NACC; ++j) acc4[j] *= rr4;
            for (int e = 0; e < ce; ++e) {
                float w = w_lds[e * 32 + h];
                f32x4 w4 = {w, w, w, w};
                const f32x4* xv = reinterpret_cast<const f32x4*>(&x_lds[e * CP + cbase]);
#pragma unroll
                for (int j = 0; j < NACC; ++j) acc4[j] += w4 * xv[j];
            }
        } else {
            floatx2 rr2 = {r, r};
#pragma unroll
            for (int j = 0; j < NACC; ++j) acc2[j] *= rr2;
            for (int e = 0; e < ce; ++e) {
                float w = w_lds[e * 32 + h];
                floatx2 w2 = {w, w};
                const floatx2* xv = reinterpret_cast<const floatx2*>(&x_lds[e * CP + cbase]);
#pragma unroll
                for (int j = 0; j < NACC; ++j) acc2[j] += w2 * xv[j];
            }
        }
    }

    float dinv = 1.f / d_reg;
    if constexpr (V4) {
        uint2* zp = reinterpret_cast<uint2*>(
            z + (size_t)(n - n0) * (32 * CP) + h * CP + cbase);
#pragma unroll
        for (int j = 0; j < NACC; ++j) {
            uint2 t;
            t.x = cvt_pk_bf16(acc4[j][0] * dinv, acc4[j][1] * dinv);
            t.y = cvt_pk_bf16(acc4[j][2] * dinv, acc4[j][3] * dinv);
            zp[j] = t;
        }
    } else {
        unsigned int* zp = reinterpret_cast<unsigned int*>(
            z + (size_t)(n - n0) * (32 * CP) + h * CP + cbase);
#pragma unroll
        for (int j = 0; j < NACC; ++j)
            zp[j] = cvt_pk_bf16(acc2[j][0] * dinv, acc2[j][1] * dinv);
    }
}

// ---------------- pass B: LDS-tiled MFMA GEMM (MT=64) ----------------
// runtime nr (row count); FB path optionally emits per-channel BN stat partials
// (NT==1 layers) via a deterministic LDS tree.
template <int NT, int KP, int KS, bool FB, bool STATS>
__global__ __launch_bounds__(256) void gemm_z_t(const unsigned short* __restrict__ z,
                                                const unsigned short* __restrict__ Wt,
                                                float* __restrict__ obuf,
                                                const float* __restrict__ bias,
                                                int n0, int COUT, int nr,
                                                float* __restrict__ statp) {
    constexpr int NP = NT * 16;
    constexpr int KSEG = KP / KS;       // multiple of 64
    constexpr int NC = KSEG / 64;
    constexpr int MT = 64;
    __shared__ unsigned short Abuf[2][MT * 64];
    __shared__ unsigned short Bbuf[2][NP * 64];

    const int m0 = blockIdx.x * MT;
    const int kbeg = blockIdx.y * KSEG;
    const int tid = threadIdx.x;
    const int wv = tid >> 6;
    const int lane = tid & 63;
    const int mm = lane & 15, quad = lane >> 4;

    auto stage = [&](int buf, int kk) {
#pragma unroll
        for (int it = 0; it < 2; ++it) {
            int gi = it * 256 + tid;
            int row = gi >> 3, gc = gi & 7;
            int srow = m0 + row;
            if (srow > nr - 1) srow = nr - 1;
            const unsigned short* src = z + (size_t)srow * KP + kk + gc * 8;
            unsigned short* dst = &Abuf[buf][(size_t)(it * 256 + wv * 64) * 8];
            load_lds16(src, dst);
        }
#pragma unroll
        for (int it = 0; it < (NP * 8 + 255) / 256; ++it) {
            int gi = it * 256 + tid;
            if (gi < NP * 8) {
                int row = gi >> 3, gc = gi & 7;
                const unsigned short* src = Wt + (size_t)row * KP + kk + gc * 8;
                unsigned short* dst = &Bbuf[buf][(size_t)(it * 256 + wv * 64) * 8];
                load_lds16(src, dst);
            }
        }
    };

    f32x4 acc[NT];
#pragma unroll
    for (int t = 0; t < NT; ++t) acc[t] = f32x4{0.f, 0.f, 0.f, 0.f};

    stage(0, kbeg);
    for (int c = 0; c < NC; ++c) {
        asm volatile("s_waitcnt vmcnt(0)" ::: "memory");
        __syncthreads();
        int cur = c & 1;
        if (c + 1 < NC) stage(cur ^ 1, kbeg + (c + 1) * 64);
        const unsigned short* Ab = Abuf[cur];
        const unsigned short* Bb = Bbuf[cur];
#pragma unroll
        for (int hh = 0; hh < 2; ++hh) {
            bf16x8 a0 = *reinterpret_cast<const bf16x8*>(&Ab[(wv * 16 + mm) * 64 + hh * 32 + quad * 8]);
#pragma unroll
            for (int t = 0; t < NT; ++t) {
                bf16x8 b = *reinterpret_cast<const bf16x8*>(&Bb[(t * 16 + mm) * 64 + hh * 32 + quad * 8]);
                acc[t] = __builtin_amdgcn_mfma_f32_16x16x32_bf16(a0, b, acc[t], 0, 0, 0);
            }
        }
        __syncthreads();
    }

    int row0 = quad * 4;
    if constexpr (FB) {
        float s = 0.f, q = 0.f;
#pragma unroll
        for (int t = 0; t < NT; ++t) {
            int cc = t * 16 + mm;
#pragma unroll
            for (int r = 0; r < 4; ++r) {
                int m = m0 + wv * 16 + row0 + r;
                if (m < nr && cc < COUT) {
                    float v = acc[t][r] + bias[cc];
                    v = v > 0.f ? v : 0.01f * v;
                    obuf[(size_t)(n0 + m) * COUT + cc] = v;
                    if constexpr (STATS) { s += v; q += v * v; }
                }
            }
        }
        if constexpr (STATS) {
            static_assert(NT == 1, "STATS path assumes NT==1");
            __shared__ float ssum[4][4][16], sqsum[4][4][16];
            ssum[wv][quad][mm] = s; sqsum[wv][quad][mm] = q;
            __syncthreads();
            if (tid < 16) {
                float S = 0.f, Q = 0.f;
#pragma unroll
                for (int a = 0; a < 4; ++a)
#pragma unroll
                    for (int b2 = 0; b2 < 4; ++b2) {
                        S += ssum[a][b2][tid]; Q += sqsum[a][b2][tid];
                    }
                if (tid < COUT) {
                    statp[(size_t)blockIdx.x * 2 * COUT + tid] = S;
                    statp[(size_t)blockIdx.x * 2 * COUT + COUT + tid] = Q;
                }
            }
        }
    } else {
        float* pb = obuf + (size_t)blockIdx.y * MPAD * NP;
#pragma unroll
        for (int t = 0; t < NT; ++t) {
            int cc = t * 16 + mm;
#pragma unroll
            for (int r = 0; r < 4; ++r) {
                int m = m0 + wv * 16 + row0 + r;
                pb[(size_t)m * NP + cc] = acc[t][r];
            }
        }
    }
}

// reduce K-split partials + bias + leaky 0.01 -> xout (r24 fully-parallel form)
__global__ void reduce_parts(const float* __restrict__ pbuf, int KS, int NPAD, int COUT,
                             const float* __restrict__ bias, int n0,
                             float* __restrict__ xout) {
    int idx = blockIdx.x * blockDim.x + threadIdx.x;
    if (idx >= NSLAB * NPAD) return;
    int m = idx / NPAD, c = idx % NPAD;
    if (c >= COUT) return;
    float s = 0.f;
    for (int p = 0; p < KS; ++p) s += pbuf[(size_t)p * MPAD * NPAD + (size_t)m * NPAD + c];
    float v = s + bias[c];
    v = v > 0.f ? v : 0.01f * v;
    xout[(size_t)(n0 + m) * COUT + c] = v;
}

// ---------------- fused mean-pool + FC + sigmoid ----------------
__global__ __launch_bounds__(64) void pool_head(const float* __restrict__ x4,
                                                const int* __restrict__ batch,
                                                const float* __restrict__ cond,
                                                const float* __restrict__ fcW,
                                                const float* __restrict__ fcb,
                                                float* __restrict__ out) {
    int g = blockIdx.x;
    int lane = threadIdx.x;
    int lo = 0, hi = NN;
    while (lo < hi) { int mid = (lo + hi) >> 1; if (batch[mid] < g) lo = mid + 1; else hi = mid; }
    int lo2 = lo, hi2 = NN;
    while (lo2 < hi2) { int mid = (lo2 + hi2) >> 1; if (batch[mid] < g + 1) lo2 = mid + 1; else hi2 = mid; }
    int beg = lo, end = lo2;

    float s[5] = {0.f, 0.f, 0.f, 0.f, 0.f};
    for (int n = beg + lane; n < end; n += 64) {
#pragma unroll
        for (int c = 0; c < 5; ++c) s[c] += x4[(size_t)n * 5 + c];
    }
    float cz = 0.f;
    if (lane < 100) cz = cond[lane] * fcW[5 + lane];
    if (lane + 64 < 100) cz += cond[lane + 64] * fcW[5 + lane + 64];
#pragma unroll
    for (int off = 32; off > 0; off >>= 1) {
#pragma unroll
        for (int c = 0; c < 5; ++c) s[c] += __shfl_down(s[c], off, 64);
        cz += __shfl_down(cz, off, 64);
    }
    if (lane == 0) {
        float cnt = fmaxf((float)(end - beg), 1.f);
        float zv = fcb[0] + cz;
#pragma unroll
        for (int c = 0; c < 5; ++c) zv += (s[c] / cnt) * fcW[c];
        out[g] = 1.f / (1.f + __expf(-zv));
    }
}

// ---------------- per-layer driver ----------------
struct LayerBufs {
    float* scale; float* shift;
    unsigned short* xbn; unsigned short* zbuf;
    float* Sbuf; float* pbuf; const int* rowptr; const int* colsrc;
};

// sp_in/nb_in: BN stat partials for THIS layer's input ([b][2][CIN], nb entries).
// statp: where the FB-gemm epilogue writes stat partials for the NEXT layer
// (single-slab OSTATS layers only).
template <int CIN, int CP, int COUT, int NP, int NT, int KS, int SLABS, bool OSTATS>
static void run_layer(const float* xin, const float* sp_in, int nb_in,
                      const float* Wf, const unsigned short* Wft,
                      const unsigned short* Wt,
                      const float* Bv, const float* G, const float* Be,
                      float* xout, float* statp, const LayerBufs& B, hipStream_t stream) {
    constexpr int KP = 32 * CP;
    constexpr int NPAD = NT * 16;
    constexpr int NR = NN / SLABS;
    bn_apply_f<CIN, CP><<<512, 256, 0, stream>>>(xin, sp_in, nb_in, G, Be,
                                                 B.scale, B.shift, B.xbn);
    if constexpr (CP >= 64) {
        gemm_s<CP><<<NN / 64, 256, 0, stream>>>(B.xbn, Wft, B.Sbuf);
    } else {
        gemm_bn<<<dim3(1, NN / 64), 256, 0, stream>>>(xin, Wf, B.scale, B.shift, CIN, 64, B.Sbuf);
    }
    for (int s = 0; s < SLABS; ++s) {
        int n0 = s * NR;
        agg_x<CIN, CP><<<NR, 256, 0, stream>>>(B.xbn, B.Sbuf, B.rowptr, B.colsrc, n0, B.zbuf);
        if constexpr (KS > 1) {
            static_assert(SLABS == 2, "K-split path assumes NSLAB rows");
            gemm_z_t<NT, KP, KS, false, false><<<dim3(MPAD / 64, KS), 256, 0, stream>>>(
                B.zbuf, Wt, B.pbuf, nullptr, n0, COUT, NR, nullptr);
            reduce_parts<<<(NSLAB * NPAD + 255) / 256, 256, 0, stream>>>(
                B.pbuf, KS, NPAD, COUT, Bv, n0, xout);
        } else {
            gemm_z_t<NT, KP, 1, true, OSTATS><<<dim3((NR + 63) / 64, 1), 256, 0, stream>>>(
                B.zbuf, Wt, xout, Bv, n0, COUT, NR, statp);
        }
    }
}

extern "C" void kernel_launch(void* const* d_in, const int* in_sizes, int n_in,
                              void* d_out, int out_size, void* d_ws, size_t ws_size,
                              hipStream_t stream) {
    (void)in_sizes; (void)n_in; (void)out_size;
    const float* x     = (const float*)d_in[0];
    const int*   ei    = (const int*)d_in[1];
    const int*   batch = (const int*)d_in[2];
    const float* cond  = (const float*)d_in[3];
    const float* W[4]  = {(const float*)d_in[4],  (const float*)d_in[8],
                          (const float*)d_in[12], (const float*)d_in[16]};
    const float* Asp[4] = {(const float*)d_in[5],  (const float*)d_in[9],
                           (const float*)d_in[13], (const float*)d_in[17]};
    const float* Adp[4] = {(const float*)d_in[6],  (const float*)d_in[10],
                           (const float*)d_in[14], (const float*)d_in[18]};
    const float* Bv[4]  = {(const float*)d_in[7],  (const float*)d_in[11],
                           (const float*)d_in[15], (const float*)d_in[19]};
    const float* G[4]   = {(const float*)d_in[20], (const float*)d_in[22],
                           (const float*)d_in[24], (const float*)d_in[26]};
    const float* Be[4]  = {(const float*)d_in[21], (const float*)d_in[23],
                           (const float*)d_in[25], (const float*)d_in[27]};
    const float* fcW = (const float*)d_in[30];
    const float* fcb = (const float*)d_in[31];
    float* out = (float*)d_out;

    char* base = (char*)d_ws;
    size_t off = 0;
    auto alloc = [&](size_t b) {
        size_t o = off;
        off += (b + 255) & ~(size_t)255;
        return (void*)(base + o);
    };
    unsigned short* zbuf = (unsigned short*)alloc((size_t)NSLAB * 4096 * 2);
    unsigned short* xbn  = (unsigned short*)alloc((size_t)NN * 128 * 2);
    float* pbuf    = (float*)alloc((size_t)4 * MPAD * 96 * 4);
    float* xbuf    = (float*)alloc((size_t)NN * 90 * 4);
    float* Sbuf    = (float*)alloc((size_t)NN * 64 * 4);
    float* partial = (float*)alloc((size_t)NPB * 2 * 128 * 4);
    float* stat1   = (float*)alloc((size_t)NPB * 2 * 128 * 4);
    float* scale   = (float*)alloc(128 * 4);
    float* shift   = (float*)alloc(128 * 4);
    // per-layer weight buffers (prep hoisted to one upfront dispatch)
    const int CPs[4]  = {128, 96, 48, 16};
    const int NPs[4]  = {96, 48, 16, 16};
    const int CINs[4] = {128, 90, 45, 15};
    const int COUTs[4] = {90, 45, 15, 5};
    float* Wf_a[4]; unsigned short* Wft_a[4]; unsigned short* Wt_a[4];
    for (int i = 0; i < 4; ++i) {
        Wf_a[i]  = (float*)alloc((size_t)CPs[i] * 64 * 4);
        Wft_a[i] = (unsigned short*)alloc((size_t)64 * CPs[i] * 2);
        Wt_a[i]  = (unsigned short*)alloc((size_t)NPs[i] * 32 * CPs[i] * 2);
    }
    int* deg     = (int*)alloc((size_t)NN * 4);
    int* rowptr  = (int*)alloc((size_t)(NN + 1) * 4);
    int* cursor  = (int*)alloc((size_t)NN * 4);
    int* colsrc  = (int*)alloc((size_t)(NE + NN) * 4);
    int* bsum    = (int*)alloc((size_t)SCB * 4);
    int* boff    = (int*)alloc((size_t)SCB * 4);
    if (off > ws_size) return;

    const int* srcp = ei;
    const int* dstp = ei + NE;

    // all-layer weight prep in one dispatch, first (independent of everything)
    PrepArgs PA;
    int bb = 0;
    for (int i = 0; i < 4; ++i) {
        PA.L[i] = PrepLayer{W[i], Asp[i], Adp[i], Wf_a[i], Wft_a[i], Wt_a[i],
                            CINs[i], CPs[i], COUTs[i], NPs[i], bb};
        bb += CPs[i] + NPs[i];
    }
    PA.nb = bb;
    prep_all<<<bb, 256, 0, stream>>>(PA);

    // CSR by dst (hierarchical scan); deg zeroed via memset, self-loop +1 in scans
    hipMemsetAsync(deg, 0, (size_t)NN * 4, stream);
    count_kernel<<<(NE + 255) / 256, 256, 0, stream>>>(dstp, deg);
    scan_pass1<<<SCB, 256, 0, stream>>>(deg, bsum);
    scan_pass2<<<1, 256, 0, stream>>>(bsum, boff, rowptr);
    scan_pass3<<<SCB, 256, 0, stream>>>(deg, boff, rowptr, cursor);
    scatter_all<<<(NE + NN + 255) / 256, 256, 0, stream>>>(srcp, dstp, cursor, colsrc);

    LayerBufs B{scale, shift, xbn, zbuf, Sbuf, pbuf, rowptr, colsrc};

    // L1: 128->90 (2 slabs, KS=4); input stats from raw x
    bn_partial<<<NPB, 128, 0, stream>>>(x, NN, 128, partial);
    run_layer<128, 128, 90, 96, 6, 4, 2, false>(x, partial, NPB,
        Wf_a[0], Wft_a[0], Wt_a[0], Bv[0], G[0], Be[0], xbuf, nullptr, B, stream);
    // L2: 90->45 (2 slabs, KS=3); input stats via bn_partial on L1 output
    bn_partial<<<NPB, 128, 0, stream>>>(xbuf, NN, 90, partial);
    run_layer< 90,  96, 45, 48, 3, 3, 2, false>(xbuf, partial, NPB,
        Wf_a[1], Wft_a[1], Wt_a[1], Bv[1], G[1], Be[1], xbuf, nullptr, B, stream);
    // L3: 45->15 (single slab; FB gemm emits stats -> stat1, nb=625)
    bn_partial<<<NPB, 128, 0, stream>>>(xbuf, NN, 45, partial);
    run_layer< 45,  48, 15, 16, 1, 1, 1, true >(xbuf, partial, NPB,
        Wf_a[2], Wft_a[2], Wt_a[2], Bv[2], G[2], Be[2], xbuf, stat1, B, stream);
    // L4: 15->5 (single slab, no downstream BN)
    run_layer< 15,  16,  5, 16, 1, 1, 1, false>(xbuf, stat1, 625,
        Wf_a[3], Wft_a[3], Wt_a[3], Bv[3], G[3], Be[3], xbuf, nullptr, B, stream);

    pool_head<<<256, 64, 0, stream>>>(xbuf, batch, cond, fcW, fcb, out);
}

// Round 12
// 952.810 us; speedup vs baseline: 1.5135x; 1.2486x over previous
//
#include <hip/hip_runtime.h>
#include <hip/hip_bf16.h>

// ---------------- constants ----------------
constexpr int NN = 40000;   // nodes
constexpr int NE = 400000;  // edges (before self-loops)
constexpr int NSLAB = 20000;
constexpr int MPAD = 20096; // 157 * 128 (M-tile overrun padding; 314 * 64)
constexpr int SCB = 256;    // scan blocks
constexpr int SCHUNK = (NN + SCB - 1) / SCB;   // 157 (<= 256)
constexpr int NPB = 512;    // bn_partial blocks (rows of `partial`)

__device__ __forceinline__ unsigned short f2bf(float f) {
    unsigned int u = __float_as_uint(f);
    unsigned int r = (u + 0x7FFFu + ((u >> 16) & 1u)) >> 16;
    return (unsigned short)r;
}

// packed f32x2 -> bf16x2, RTNE (bit-identical to f2bf pairs), 1 instruction
__device__ __forceinline__ unsigned int cvt_pk_bf16(float a, float b) {
    unsigned int r;
    asm("v_cvt_pk_bf16_f32 %0, %1, %2" : "=v"(r) : "v"(a), "v"(b));
    return r;
}

// async global->LDS 16B: no VGPR round-trip, loads issue back-to-back.
__device__ __forceinline__ void load_lds16(const unsigned short* g, unsigned short* l) {
    __builtin_amdgcn_global_load_lds(
        (const __attribute__((address_space(1))) unsigned int*)(g),
        (__attribute__((address_space(3))) unsigned int*)(l), 16, 0, 0);
}

typedef __attribute__((ext_vector_type(8))) short bf16x8;
typedef __attribute__((ext_vector_type(4))) float f32x4;
typedef __attribute__((ext_vector_type(2))) float floatx2;

// ---------------- BN ----------------
__global__ void bn_partial(const float* __restrict__ x, int N, int C,
                           float* __restrict__ partial) {
    int ch = threadIdx.x;            // blockDim = 128, C <= 128
    if (ch >= C) return;
    float s = 0.f, sq = 0.f;
    for (int n = blockIdx.x; n < N; n += gridDim.x) {
        float v = x[(size_t)n * C + ch];
        s += v; sq += v * v;
    }
    partial[(size_t)blockIdx.x * 2 * C + ch]     = s;
    partial[(size_t)blockIdx.x * 2 * C + C + ch] = sq;
}

// fused finalize + apply. NB is COMPILE-TIME (r27 fix: r26's runtime nb defeated
// unrolling -> 82us latency-chain prologue; template NB restores ILP).
template <int CIN, int CP, int NB>
__global__ __launch_bounds__(256) void bn_apply_f(const float* __restrict__ x,
                                                  const float* __restrict__ partial,
                                                  const float* __restrict__ g,
                                                  const float* __restrict__ be,
                                                  float* __restrict__ scale_g,
                                                  float* __restrict__ shift_g,
                                                  unsigned short* __restrict__ xbn) {
    __shared__ float hs[2][128], hq[2][128];
    __shared__ float sc_l[CP], sh_l[CP];
    const int tid = threadIdx.x;
    const int half = tid >> 7, ch = tid & 127;
    if (ch < CIN) {
        constexpr int H = NB / 2;
        int b0 = half ? H : 0;
        int b1 = half ? NB : H;
        float s = 0.f, sq = 0.f;
#pragma unroll 8
        for (int b = b0; b < b1; ++b) {
            s  += partial[(size_t)b * 2 * CIN + ch];
            sq += partial[(size_t)b * 2 * CIN + CIN + ch];
        }
        hs[half][ch] = s; hq[half][ch] = sq;
    }
    __syncthreads();
    if (tid < CP) {
        float sc = 0.f, sh = 0.f;
        if (tid < CIN) {
            float s  = hs[0][tid] + hs[1][tid];
            float sq = hq[0][tid] + hq[1][tid];
            float mean = s / (float)NN;
            float var  = sq / (float)NN - mean * mean;
            float inv  = rsqrtf(var + 1e-5f);
            sc = g[tid] * inv;
            sh = be[tid] - mean * sc;
            if (blockIdx.x == 0) { scale_g[tid] = sc; shift_g[tid] = sh; }
        }
        sc_l[tid] = sc; sh_l[tid] = sh;
    }
    __syncthreads();
    const int total = NN * (CP / 2);
    for (int idx = blockIdx.x * 256 + tid; idx < total; idx += 256 * gridDim.x) {
        int n = idx / (CP / 2), c2 = idx % (CP / 2);
        int c = 2 * c2;
        float v0 = 0.f, v1 = 0.f;
        if (c < CIN)     v0 = sc_l[c] * x[(size_t)n * CIN + c] + sh_l[c];
        if (c + 1 < CIN) v1 = sc_l[c + 1] * x[(size_t)n * CIN + c + 1] + sh_l[c + 1];
        reinterpret_cast<unsigned int*>(xbn)[idx] = cvt_pk_bf16(v0, v1);
    }
}

// ---------------- fused weight prep for ALL layers in ONE dispatch (r20) ----------
struct PrepLayer {
    const float* W; const float* as_; const float* ad_;
    float* Wf; unsigned short* Wft; unsigned short* Wt;
    int CIN, CP, COUT, NP, bbase;
};
struct PrepArgs { PrepLayer L[4]; int nb; };

__global__ void prep_all(PrepArgs A) {
    int bid = blockIdx.x;
    int li = 0;
#pragma unroll
    for (int i = 1; i < 4; ++i)
        if (bid >= A.L[i].bbase) li = i;
    const PrepLayer& P = A.L[li];
    const int CIN = P.CIN, CP = P.CP, COUT = P.COUT;
    int b = bid - P.bbase;
    int tid = threadIdx.x;
    if (b < CP) {
        int cin = b;
        if (tid < 64) {
            int j = tid, h = j & 31;
            float s = 0.f;
            if (cin < CIN) {
                const float* a = (j < 32) ? P.as_ : P.ad_;
                const float* wrow = P.W + (size_t)cin * 32 * COUT + (size_t)h * COUT;
                const float* arow = a + (size_t)h * COUT;
                for (int c = 0; c < COUT; ++c) s += wrow[c] * arow[c];
            }
            P.Wf[cin * 64 + j] = s;
            P.Wft[j * CP + cin] = f2bf(s);
        }
    } else {
        int c = b - CP;   // [0, NP)
        for (int kk = tid; kk < 32 * CP; kk += blockDim.x) {
            int h = kk / CP, k = kk % CP;
            float v = 0.f;
            if (k < CIN && c < COUT)
                v = P.W[(size_t)k * (32 * COUT) + h * COUT + c] * (1.f / 32.f);
            P.Wt[(size_t)c * (32 * CP) + kk] = f2bf(v);
        }
    }
}

// ---------------- MFMA score GEMM: Sbuf[n, 0:64] = xbn[n,:] @ Wft^T ------------------
template <int CPK>
__global__ __launch_bounds__(256) void gemm_s(const unsigned short* __restrict__ xbn,
                                              const unsigned short* __restrict__ Wft,
                                              float* __restrict__ Sbuf) {
    constexpr int NC = CPK / 32;
    __shared__ unsigned short Ab[64 * 32];
    __shared__ unsigned short Bb[64 * 32];
    const int m0 = blockIdx.x * 64;
    const int tid = threadIdx.x;
    const int wv = tid >> 6, lane = tid & 63;
    const int mm = lane & 15, quad = lane >> 4;
    f32x4 acc[4];
#pragma unroll
    for (int t = 0; t < 4; ++t) acc[t] = f32x4{0.f, 0.f, 0.f, 0.f};

    for (int c = 0; c < NC; ++c) {
        int row = tid >> 2, gc = tid & 3;
        load_lds16(xbn + (size_t)(m0 + row) * CPK + c * 32 + gc * 8, Ab + (size_t)tid * 8);
        load_lds16(Wft + (size_t)row * CPK + c * 32 + gc * 8, Bb + (size_t)tid * 8);
        asm volatile("s_waitcnt vmcnt(0)" ::: "memory");
        __syncthreads();
        bf16x8 a = *reinterpret_cast<const bf16x8*>(&Ab[(wv * 16 + mm) * 32 + quad * 8]);
#pragma unroll
        for (int t = 0; t < 4; ++t) {
            bf16x8 b = *reinterpret_cast<const bf16x8*>(&Bb[(t * 16 + mm) * 32 + quad * 8]);
            acc[t] = __builtin_amdgcn_mfma_f32_16x16x32_bf16(a, b, acc[t], 0, 0, 0);
        }
        __syncthreads();
    }
    int rbase = m0 + wv * 16 + quad * 4;
#pragma unroll
    for (int t = 0; t < 4; ++t)
#pragma unroll
        for (int r = 0; r < 4; ++r)
            Sbuf[(size_t)(rbase + r) * 64 + t * 16 + mm] = acc[t][r];
}

// ---------------- fp32 GEMM with fused BN on A (score GEMM for small-K layers) ----
__global__ __launch_bounds__(256) void gemm_bn(const float* __restrict__ X,
                                               const float* __restrict__ W,
                                               const float* __restrict__ scale,
                                               const float* __restrict__ shift,
                                               int Cin, int HC, float* __restrict__ OUT) {
    __shared__ float As[8][64];
    __shared__ float Bs[8][64];
    int tid = threadIdx.x;
    int n0 = blockIdx.y * 64;
    int j0 = blockIdx.x * 64;
    int tr = tid >> 4, tc = tid & 15;
    float acc[4][4] = {};
    for (int k0 = 0; k0 < Cin; k0 += 8) {
        int idx = tid;
#pragma unroll
        for (int it = 0; it < 2; ++it, idx += 256) {
            int row = idx >> 3, kk = idx & 7;
            int k = k0 + kk;
            float v = 0.f;
            if (k < Cin) v = scale[k] * X[(size_t)(n0 + row) * Cin + k] + shift[k];
            As[kk][row] = v;
        }
        int idx2 = tid;
#pragma unroll
        for (int it = 0; it < 2; ++it, idx2 += 256) {
            int col = idx2 & 63, kr = idx2 >> 6;
            int k = k0 + kr, j = j0 + col;
            float v = 0.f;
            if (k < Cin && j < HC) v = W[(size_t)k * HC + j];
            Bs[kr][col] = v;
        }
        __syncthreads();
#pragma unroll
        for (int kk = 0; kk < 8; ++kk) {
            float a[4], b[4];
#pragma unroll
            for (int i = 0; i < 4; ++i) a[i] = As[kk][tr * 4 + i];
#pragma unroll
            for (int j = 0; j < 4; ++j) b[j] = Bs[kk][tc * 4 + j];
#pragma unroll
            for (int i = 0; i < 4; ++i)
#pragma unroll
                for (int j = 0; j < 4; ++j) acc[i][j] += a[i] * b[j];
        }
        __syncthreads();
    }
#pragma unroll
    for (int i = 0; i < 4; ++i) {
        int row = n0 + tr * 4 + i;
#pragma unroll
        for (int j = 0; j < 4; ++j) {
            int col = j0 + tc * 4 + j;
            if (col < HC) OUT[(size_t)row * HC + col] = acc[i][j];
        }
    }
}

// ---------------- CSR build (hierarchical 3-pass scan) ----------------
__global__ void count_kernel(const int* __restrict__ dst, int* __restrict__ deg) {
    int e = blockIdx.x * blockDim.x + threadIdx.x;
    if (e < NE) atomicAdd(&deg[dst[e]], 1);
}
__global__ void scan_pass1(const int* __restrict__ deg, int* __restrict__ bsum) {
    __shared__ int red[256];
    int b = blockIdx.x, t = threadIdx.x;
    int lo = b * SCHUNK, hi = min(lo + SCHUNK, NN);
    int s = 0;
    for (int i = lo + t; i < hi; i += 256) s += deg[i] + 1;   // +1 self-loop
    red[t] = s;
    __syncthreads();
    for (int off = 128; off > 0; off >>= 1) {
        if (t < off) red[t] += red[t + off];
        __syncthreads();
    }
    if (t == 0) bsum[b] = red[0];
}
__global__ void scan_pass2(const int* __restrict__ bsum, int* __restrict__ boff,
                           int* __restrict__ rowptr) {
    __shared__ int lds[256];
    int t = threadIdx.x;
    int v0 = bsum[t];
    lds[t] = v0;
    __syncthreads();
    for (int off = 1; off < 256; off <<= 1) {
        int v = (t >= off) ? lds[t - off] : 0;
        __syncthreads();
        lds[t] += v;
        __syncthreads();
    }
    boff[t] = lds[t] - v0;          // exclusive
    if (t == 255) rowptr[NN] = lds[255];
}
__global__ void scan_pass3(const int* __restrict__ deg, const int* __restrict__ boff,
                           int* __restrict__ rowptr, int* __restrict__ cursor) {
    __shared__ int lds[256];
    int b = blockIdx.x, t = threadIdx.x;
    int i = b * SCHUNK + t;
    int d = (t < SCHUNK && i < NN) ? (deg[i] + 1) : 0;   // +1 self-loop
    lds[t] = d;
    __syncthreads();
    for (int off = 1; off < 256; off <<= 1) {
        int v = (t >= off) ? lds[t - off] : 0;
        __syncthreads();
        lds[t] += v;
        __syncthreads();
    }
    if (t < SCHUNK && i < NN) {
        int excl = lds[t] - d + boff[b];
        rowptr[i] = excl;
        cursor[i] = excl;
    }
}
__global__ void scatter_all(const int* __restrict__ src, const int* __restrict__ dst,
                            int* __restrict__ cursor, int* __restrict__ colsrc) {
    int e = blockIdx.x * blockDim.x + threadIdx.x;
    if (e < NE) {
        int pos = atomicAdd(&cursor[dst[e]], 1);
        colsrc[pos] = src[e];
    } else if (e < NE + NN) {
        int n = e - NE;
        int pos = atomicAdd(&cursor[n], 1);
        colsrc[pos] = n;
    }
}

// ---------------- pass A: softmax-aggregate xbn -> z[n, 32*CP] (bf16) ----------------
// Proven r21 form (block-per-node, CH=16, direct uint2 stores, conflicts 0).
template <int CIN, int CP>
__global__ __launch_bounds__(256) void agg_x(const unsigned short* __restrict__ xbn,
                                             const float* __restrict__ S,
                                             const int* __restrict__ rowptr,
                                             const int* __restrict__ colsrc,
                                             int n0, unsigned short* __restrict__ z) {
    constexpr int BS = 256, CH = 16, J = CP / 8;   // J = 16,12,6,2
    constexpr bool V4 = (J % 4 == 0);
    constexpr int NACC = V4 ? (J / 4) : (J / 2);
    constexpr int LIT = CH * 32 / 256;             // 2 logit iterations
    __shared__ __align__(16) float x_lds[CH * CP];
    __shared__ float w_lds[CH * 32];
    __shared__ int cs_lds[CH];
    __shared__ float red_m[8][32];
    __shared__ float red_s[8][32];

    int n = n0 + blockIdx.x;
    int tid = threadIdx.x;
    int start = rowptr[n], end = rowptr[n + 1];
    const int h = tid & 31, g = tid >> 5;
    const int cbase = g * J;
    const float sd = S[(size_t)n * 64 + 32 + h];   // broadcast within head column

    float m_reg = -INFINITY, d_reg = 0.f;
    f32x4 acc4[V4 ? NACC : 1];
    floatx2 acc2[V4 ? 1 : NACC];
    if constexpr (V4) {
#pragma unroll
        for (int j = 0; j < NACC; ++j) acc4[j] = f32x4{0.f, 0.f, 0.f, 0.f};
    } else {
#pragma unroll
        for (int j = 0; j < NACC; ++j) acc2[j] = floatx2{0.f, 0.f};
    }

    for (int chunk = start; chunk < end; chunk += CH) {
        int ce = min(CH, end - chunk);
        int ce32 = ce * 32;
        if (tid < CH && tid < ce) cs_lds[tid] = colsrc[chunk + tid];
        __syncthreads();   // B1: cs_lds visible

        float lreg[LIT];
        float pmx = -INFINITY;
#pragma unroll
        for (int p = 0; p < LIT; ++p) {
            int idx = p * 256 + tid;
            lreg[p] = -INFINITY;
            if (idx < ce32) {
                int e = idx >> 5;
                float l = S[(size_t)cs_lds[e] * 64 + h] + sd;
                l = l > 0.f ? l : 0.2f * l;
                lreg[p] = l;
                pmx = fmaxf(pmx, l);
            }
        }
        red_m[g][h] = pmx;
        // stage x rows (bf16 -> f32) via uint2, f32x4 stores
        for (int idx = tid; idx < ce * (CP / 4); idx += BS) {
            int e = idx / (CP / 4), c4 = idx % (CP / 4);
            uint2 u = reinterpret_cast<const uint2*>(xbn)[(size_t)cs_lds[e] * (CP / 4) + c4];
            f32x4 t;
            t[0] = __uint_as_float(u.x << 16);
            t[1] = __uint_as_float(u.x & 0xFFFF0000u);
            t[2] = __uint_as_float(u.y << 16);
            t[3] = __uint_as_float(u.y & 0xFFFF0000u);
            *reinterpret_cast<f32x4*>(&x_lds[e * CP + 4 * c4]) = t;
        }
        __syncthreads();   // B2: red_m + x_lds visible

        // per-thread redundant max reduce (identical order to serial version)
        float cm = red_m[0][h];
#pragma unroll
        for (int s2 = 1; s2 < 8; ++s2) cm = fmaxf(cm, red_m[s2][h]);
        float newm = fmaxf(m_reg, cm);
        float r = (m_reg == -INFINITY) ? 0.f : __expf(m_reg - newm);
        m_reg = newm;

        float ps = 0.f;
#pragma unroll
        for (int p = 0; p < LIT; ++p) {
            int idx = p * 256 + tid;
            if (idx < ce32) {
                float v = __expf(lreg[p] - m_reg);
                w_lds[idx] = v;
                ps += v;
            }
        }
        red_s[g][h] = ps;
        __syncthreads();   // B3: w_lds + red_s visible

        float ss = red_s[0][h];
#pragma unroll
        for (int s2 = 1; s2 < 8; ++s2) ss += red_s[s2][h];
        d_reg = d_reg * r + ss;

        if constexpr (V4) {
            f32x4 rr4 = {r, r, r, r};
#pragma unroll
            for (int j = 0; j < NACC; ++j) acc4[j] *= rr4;
            for (int e = 0; e < ce; ++e) {
                float w = w_lds[e * 32 + h];
                f32x4 w4 = {w, w, w, w};
                const f32x4* xv = reinterpret_cast<const f32x4*>(&x_lds[e * CP + cbase]);
#pragma unroll
                for (int j = 0; j < NACC; ++j) acc4[j] += w4 * xv[j];
            }
        } else {
            floatx2 rr2 = {r, r};
#pragma unroll
            for (int j = 0; j < NACC; ++j) acc2[j] *= rr2;
            for (int e = 0; e < ce; ++e) {
                float w = w_lds[e * 32 + h];
                floatx2 w2 = {w, w};
                const floatx2* xv = reinterpret_cast<const floatx2*>(&x_lds[e * CP + cbase]);
#pragma unroll
                for (int j = 0; j < NACC; ++j) acc2[j] += w2 * xv[j];
            }
        }
    }

    float dinv = 1.f / d_reg;
    if constexpr (V4) {
        uint2* zp = reinterpret_cast<uint2*>(
            z + (size_t)(n - n0) * (32 * CP) + h * CP + cbase);
#pragma unroll
        for (int j = 0; j < NACC; ++j) {
            uint2 t;
            t.x = cvt_pk_bf16(acc4[j][0] * dinv, acc4[j][1] * dinv);
            t.y = cvt_pk_bf16(acc4[j][2] * dinv, acc4[j][3] * dinv);
            zp[j] = t;
        }
    } else {
        unsigned int* zp = reinterpret_cast<unsigned int*>(
            z + (size_t)(n - n0) * (32 * CP) + h * CP + cbase);
#pragma unroll
        for (int j = 0; j < NACC; ++j)
            zp[j] = cvt_pk_bf16(acc2[j][0] * dinv, acc2[j][1] * dinv);
    }
}

// ---------------- pass B: LDS-tiled MFMA GEMM (MT=64) ----------------
// runtime nr (row count); FB path optionally emits per-channel BN stat partials
// (NT==1 layers) via a deterministic LDS tree.
template <int NT, int KP, int KS, bool FB, bool STATS>
__global__ __launch_bounds__(256) void gemm_z_t(const unsigned short* __restrict__ z,
                                                const unsigned short* __restrict__ Wt,
                                                float* __restrict__ obuf,
                                                const float* __restrict__ bias,
                                                int n0, int COUT, int nr,
                                                float* __restrict__ statp) {
    constexpr int NP = NT * 16;
    constexpr int KSEG = KP / KS;       // multiple of 64
    constexpr int NC = KSEG / 64;
    constexpr int MT = 64;
    __shared__ unsigned short Abuf[2][MT * 64];
    __shared__ unsigned short Bbuf[2][NP * 64];

    const int m0 = blockIdx.x * MT;
    const int kbeg = blockIdx.y * KSEG;
    const int tid = threadIdx.x;
    const int wv = tid >> 6;
    const int lane = tid & 63;
    const int mm = lane & 15, quad = lane >> 4;

    auto stage = [&](int buf, int kk) {
#pragma unroll
        for (int it = 0; it < 2; ++it) {
            int gi = it * 256 + tid;
            int row = gi >> 3, gc = gi & 7;
            int srow = m0 + row;
            if (srow > nr - 1) srow = nr - 1;
            const unsigned short* src = z + (size_t)srow * KP + kk + gc * 8;
            unsigned short* dst = &Abuf[buf][(size_t)(it * 256 + wv * 64) * 8];
            load_lds16(src, dst);
        }
#pragma unroll
        for (int it = 0; it < (NP * 8 + 255) / 256; ++it) {
            int gi = it * 256 + tid;
            if (gi < NP * 8) {
                int row = gi >> 3, gc = gi & 7;
                const unsigned short* src = Wt + (size_t)row * KP + kk + gc * 8;
                unsigned short* dst = &Bbuf[buf][(size_t)(it * 256 + wv * 64) * 8];
                load_lds16(src, dst);
            }
        }
    };

    f32x4 acc[NT];
#pragma unroll
    for (int t = 0; t < NT; ++t) acc[t] = f32x4{0.f, 0.f, 0.f, 0.f};

    stage(0, kbeg);
    for (int c = 0; c < NC; ++c) {
        asm volatile("s_waitcnt vmcnt(0)" ::: "memory");
        __syncthreads();
        int cur = c & 1;
        if (c + 1 < NC) stage(cur ^ 1, kbeg + (c + 1) * 64);
        const unsigned short* Ab = Abuf[cur];
        const unsigned short* Bb = Bbuf[cur];
#pragma unroll
        for (int hh = 0; hh < 2; ++hh) {
            bf16x8 a0 = *reinterpret_cast<const bf16x8*>(&Ab[(wv * 16 + mm) * 64 + hh * 32 + quad * 8]);
#pragma unroll
            for (int t = 0; t < NT; ++t) {
                bf16x8 b = *reinterpret_cast<const bf16x8*>(&Bb[(t * 16 + mm) * 64 + hh * 32 + quad * 8]);
                acc[t] = __builtin_amdgcn_mfma_f32_16x16x32_bf16(a0, b, acc[t], 0, 0, 0);
            }
        }
        __syncthreads();
    }

    int row0 = quad * 4;
    if constexpr (FB) {
        float s = 0.f, q = 0.f;
#pragma unroll
        for (int t = 0; t < NT; ++t) {
            int cc = t * 16 + mm;
#pragma unroll
            for (int r = 0; r < 4; ++r) {
                int m = m0 + wv * 16 + row0 + r;
                if (m < nr && cc < COUT) {
                    float v = acc[t][r] + bias[cc];
                    v = v > 0.f ? v : 0.01f * v;
                    obuf[(size_t)(n0 + m) * COUT + cc] = v;
                    if constexpr (STATS) { s += v; q += v * v; }
                }
            }
        }
        if constexpr (STATS) {
            static_assert(NT == 1, "STATS path assumes NT==1");
            __shared__ float ssum[4][4][16], sqsum[4][4][16];
            ssum[wv][quad][mm] = s; sqsum[wv][quad][mm] = q;
            __syncthreads();
            if (tid < 16) {
                float S = 0.f, Q = 0.f;
#pragma unroll
                for (int a = 0; a < 4; ++a)
#pragma unroll
                    for (int b2 = 0; b2 < 4; ++b2) {
                        S += ssum[a][b2][tid]; Q += sqsum[a][b2][tid];
                    }
                if (tid < COUT) {
                    statp[(size_t)blockIdx.x * 2 * COUT + tid] = S;
                    statp[(size_t)blockIdx.x * 2 * COUT + COUT + tid] = Q;
                }
            }
        }
    } else {
        float* pb = obuf + (size_t)blockIdx.y * MPAD * NP;
#pragma unroll
        for (int t = 0; t < NT; ++t) {
            int cc = t * 16 + mm;
#pragma unroll
            for (int r = 0; r < 4; ++r) {
                int m = m0 + wv * 16 + row0 + r;
                pb[(size_t)m * NP + cc] = acc[t][r];
            }
        }
    }
}

// reduce K-split partials + bias + leaky 0.01 -> xout (r24 fully-parallel form)
__global__ void reduce_parts(const float* __restrict__ pbuf, int KS, int NPAD, int COUT,
                             const float* __restrict__ bias, int n0,
                             float* __restrict__ xout) {
    int idx = blockIdx.x * blockDim.x + threadIdx.x;
    if (idx >= NSLAB * NPAD) return;
    int m = idx / NPAD, c = idx % NPAD;
    if (c >= COUT) return;
    float s = 0.f;
    for (int p = 0; p < KS; ++p) s += pbuf[(size_t)p * MPAD * NPAD + (size_t)m * NPAD + c];
    float v = s + bias[c];
    v = v > 0.f ? v : 0.01f * v;
    xout[(size_t)(n0 + m) * COUT + c] = v;
}

// ---------------- fused mean-pool + FC + sigmoid ----------------
__global__ __launch_bounds__(64) void pool_head(const float* __restrict__ x4,
                                                const int* __restrict__ batch,
                                                const float* __restrict__ cond,
                                                const float* __restrict__ fcW,
                                                const float* __restrict__ fcb,
                                                float* __restrict__ out) {
    int g = blockIdx.x;
    int lane = threadIdx.x;
    int lo = 0, hi = NN;
    while (lo < hi) { int mid = (lo + hi) >> 1; if (batch[mid] < g) lo = mid + 1; else hi = mid; }
    int lo2 = lo, hi2 = NN;
    while (lo2 < hi2) { int mid = (lo2 + hi2) >> 1; if (batch[mid] < g + 1) lo2 = mid + 1; else hi2 = mid; }
    int beg = lo, end = lo2;

    float s[5] = {0.f, 0.f, 0.f, 0.f, 0.f};
    for (int n = beg + lane; n < end; n += 64) {
#pragma unroll
        for (int c = 0; c < 5; ++c) s[c] += x4[(size_t)n * 5 + c];
    }
    float cz = 0.f;
    if (lane < 100) cz = cond[lane] * fcW[5 + lane];
    if (lane + 64 < 100) cz += cond[lane + 64] * fcW[5 + lane + 64];
#pragma unroll
    for (int off = 32; off > 0; off >>= 1) {
#pragma unroll
        for (int c = 0; c < 5; ++c) s[c] += __shfl_down(s[c], off, 64);
        cz += __shfl_down(cz, off, 64);
    }
    if (lane == 0) {
        float cnt = fmaxf((float)(end - beg), 1.f);
        float zv = fcb[0] + cz;
#pragma unroll
        for (int c = 0; c < 5; ++c) zv += (s[c] / cnt) * fcW[c];
        out[g] = 1.f / (1.f + __expf(-zv));
    }
}

// ---------------- per-layer driver ----------------
struct LayerBufs {
    float* scale; float* shift;
    unsigned short* xbn; unsigned short* zbuf;
    float* Sbuf; float* pbuf; const int* rowptr; const int* colsrc;
};

// sp_in: BN stat partials for THIS layer's input ([b][2][CIN], NB entries,
// compile-time). statp: where the FB-gemm epilogue writes stat partials for the
// NEXT layer (single-slab OSTATS layers only).
template <int CIN, int CP, int COUT, int NP, int NT, int KS, int SLABS, int NB, bool OSTATS>
static void run_layer(const float* xin, const float* sp_in,
                      const float* Wf, const unsigned short* Wft,
                      const unsigned short* Wt,
                      const float* Bv, const float* G, const float* Be,
                      float* xout, float* statp, const LayerBufs& B, hipStream_t stream) {
    constexpr int KP = 32 * CP;
    constexpr int NPAD = NT * 16;
    constexpr int NR = NN / SLABS;
    bn_apply_f<CIN, CP, NB><<<512, 256, 0, stream>>>(xin, sp_in, G, Be,
                                                     B.scale, B.shift, B.xbn);
    if constexpr (CP >= 64) {
        gemm_s<CP><<<NN / 64, 256, 0, stream>>>(B.xbn, Wft, B.Sbuf);
    } else {
        gemm_bn<<<dim3(1, NN / 64), 256, 0, stream>>>(xin, Wf, B.scale, B.shift, CIN, 64, B.Sbuf);
    }
    for (int s = 0; s < SLABS; ++s) {
        int n0 = s * NR;
        agg_x<CIN, CP><<<NR, 256, 0, stream>>>(B.xbn, B.Sbuf, B.rowptr, B.colsrc, n0, B.zbuf);
        if constexpr (KS > 1) {
            static_assert(SLABS == 2, "K-split path assumes NSLAB rows");
            gemm_z_t<NT, KP, KS, false, false><<<dim3(MPAD / 64, KS), 256, 0, stream>>>(
                B.zbuf, Wt, B.pbuf, nullptr, n0, COUT, NR, nullptr);
            reduce_parts<<<(NSLAB * NPAD + 255) / 256, 256, 0, stream>>>(
                B.pbuf, KS, NPAD, COUT, Bv, n0, xout);
        } else {
            gemm_z_t<NT, KP, 1, true, OSTATS><<<dim3((NR + 63) / 64, 1), 256, 0, stream>>>(
                B.zbuf, Wt, xout, Bv, n0, COUT, NR, statp);
        }
    }
}

extern "C" void kernel_launch(void* const* d_in, const int* in_sizes, int n_in,
                              void* d_out, int out_size, void* d_ws, size_t ws_size,
                              hipStream_t stream) {
    (void)in_sizes; (void)n_in; (void)out_size;
    const float* x     = (const float*)d_in[0];
    const int*   ei    = (const int*)d_in[1];
    const int*   batch = (const int*)d_in[2];
    const float* cond  = (const float*)d_in[3];
    const float* W[4]  = {(const float*)d_in[4],  (const float*)d_in[8],
                          (const float*)d_in[12], (const float*)d_in[16]};
    const float* Asp[4] = {(const float*)d_in[5],  (const float*)d_in[9],
                           (const float*)d_in[13], (const float*)d_in[17]};
    const float* Adp[4] = {(const float*)d_in[6],  (const float*)d_in[10],
                           (const float*)d_in[14], (const float*)d_in[18]};
    const float* Bv[4]  = {(const float*)d_in[7],  (const float*)d_in[11],
                           (const float*)d_in[15], (const float*)d_in[19]};
    const float* G[4]   = {(const float*)d_in[20], (const float*)d_in[22],
                           (const float*)d_in[24], (const float*)d_in[26]};
    const float* Be[4]  = {(const float*)d_in[21], (const float*)d_in[23],
                           (const float*)d_in[25], (const float*)d_in[27]};
    const float* fcW = (const float*)d_in[30];
    const float* fcb = (const float*)d_in[31];
    float* out = (float*)d_out;

    char* base = (char*)d_ws;
    size_t off = 0;
    auto alloc = [&](size_t b) {
        size_t o = off;
        off += (b + 255) & ~(size_t)255;
        return (void*)(base + o);
    };
    unsigned short* zbuf = (unsigned short*)alloc((size_t)NSLAB * 4096 * 2);
    unsigned short* xbn  = (unsigned short*)alloc((size_t)NN * 128 * 2);
    float* pbuf    = (float*)alloc((size_t)4 * MPAD * 96 * 4);
    float* xbuf    = (float*)alloc((size_t)NN * 90 * 4);
    float* Sbuf    = (float*)alloc((size_t)NN * 64 * 4);
    float* partial = (float*)alloc((size_t)NPB * 2 * 128 * 4);
    float* stat1   = (float*)alloc((size_t)NPB * 2 * 128 * 4);
    float* scale   = (float*)alloc(128 * 4);
    float* shift   = (float*)alloc(128 * 4);
    // per-layer weight buffers (prep hoisted to one upfront dispatch)
    const int CPs[4]  = {128, 96, 48, 16};
    const int NPs[4]  = {96, 48, 16, 16};
    const int CINs[4] = {128, 90, 45, 15};
    const int COUTs[4] = {90, 45, 15, 5};
    float* Wf_a[4]; unsigned short* Wft_a[4]; unsigned short* Wt_a[4];
    for (int i = 0; i < 4; ++i) {
        Wf_a[i]  = (float*)alloc((size_t)CPs[i] * 64 * 4);
        Wft_a[i] = (unsigned short*)alloc((size_t)64 * CPs[i] * 2);
        Wt_a[i]  = (unsigned short*)alloc((size_t)NPs[i] * 32 * CPs[i] * 2);
    }
    int* deg     = (int*)alloc((size_t)NN * 4);
    int* rowptr  = (int*)alloc((size_t)(NN + 1) * 4);
    int* cursor  = (int*)alloc((size_t)NN * 4);
    int* colsrc  = (int*)alloc((size_t)(NE + NN) * 4);
    int* bsum    = (int*)alloc((size_t)SCB * 4);
    int* boff    = (int*)alloc((size_t)SCB * 4);
    if (off > ws_size) return;

    const int* srcp = ei;
    const int* dstp = ei + NE;

    // all-layer weight prep in one dispatch, first (independent of everything)
    PrepArgs PA;
    int bb = 0;
    for (int i = 0; i < 4; ++i) {
        PA.L[i] = PrepLayer{W[i], Asp[i], Adp[i], Wf_a[i], Wft_a[i], Wt_a[i],
                            CINs[i], CPs[i], COUTs[i], NPs[i], bb};
        bb += CPs[i] + NPs[i];
    }
    PA.nb = bb;
    prep_all<<<bb, 256, 0, stream>>>(PA);

    // CSR by dst (hierarchical scan); deg zeroed via memset, self-loop +1 in scans
    hipMemsetAsync(deg, 0, (size_t)NN * 4, stream);
    count_kernel<<<(NE + 255) / 256, 256, 0, stream>>>(dstp, deg);
    scan_pass1<<<SCB, 256, 0, stream>>>(deg, bsum);
    scan_pass2<<<1, 256, 0, stream>>>(bsum, boff, rowptr);
    scan_pass3<<<SCB, 256, 0, stream>>>(deg, boff, rowptr, cursor);
    scatter_all<<<(NE + NN + 255) / 256, 256, 0, stream>>>(srcp, dstp, cursor, colsrc);

    LayerBufs B{scale, shift, xbn, zbuf, Sbuf, pbuf, rowptr, colsrc};

    // L1: 128->90 (2 slabs, KS=4); input stats from raw x
    bn_partial<<<NPB, 128, 0, stream>>>(x, NN, 128, partial);
    run_layer<128, 128, 90, 96, 6, 4, 2, NPB, false>(x, partial,
        Wf_a[0], Wft_a[0], Wt_a[0], Bv[0], G[0], Be[0], xbuf, nullptr, B, stream);
    // L2: 90->45 (2 slabs, KS=3); input stats via bn_partial on L1 output
    bn_partial<<<NPB, 128, 0, stream>>>(xbuf, NN, 90, partial);
    run_layer< 90,  96, 45, 48, 3, 3, 2, NPB, false>(xbuf, partial,
        Wf_a[1], Wft_a[1], Wt_a[1], Bv[1], G[1], Be[1], xbuf, nullptr, B, stream);
    // L3: 45->15 (single slab; FB gemm emits stats -> stat1, 625 entries)
    bn_partial<<<NPB, 128, 0, stream>>>(xbuf, NN, 45, partial);
    run_layer< 45,  48, 15, 16, 1, 1, 1, NPB, true >(xbuf, partial,
        Wf_a[2], Wft_a[2], Wt_a[2], Bv[2], G[2], Be[2], xbuf, stat1, B, stream);
    // L4: 15->5 (single slab, no downstream BN); input stats from L3's epilogue
    run_layer< 15,  16,  5, 16, 1, 1, 1, 625, false>(xbuf, stat1,
        Wf_a[3], Wft_a[3], Wt_a[3], Bv[3], G[3], Be[3], xbuf, nullptr, B, stream);

    pool_head<<<256, 64, 0, stream>>>(xbuf, batch, cond, fcW, fcb, out);
}

// Round 13
// 950.968 us; speedup vs baseline: 1.5165x; 1.0019x over previous
//
#include <hip/hip_runtime.h>
#include <hip/hip_bf16.h>

// ---------------- constants ----------------
constexpr int NN = 40000;   // nodes
constexpr int NE = 400000;  // edges (before self-loops)
constexpr int NSLAB = 20000;
constexpr int MPAD = 20096; // 314 * 64 (2-slab M-tile overrun padding)
constexpr int MPADX = 40192; // part stride (rows) covering both slab modes
constexpr int SCB = 256;    // scan blocks
constexpr int SCHUNK = (NN + SCB - 1) / SCB;   // 157 (<= 256)
constexpr int NPB = 512;    // bn_partial blocks (rows of `partial`)

__device__ __forceinline__ unsigned short f2bf(float f) {
    unsigned int u = __float_as_uint(f);
    unsigned int r = (u + 0x7FFFu + ((u >> 16) & 1u)) >> 16;
    return (unsigned short)r;
}

// packed f32x2 -> bf16x2, RTNE (bit-identical to f2bf pairs), 1 instruction
__device__ __forceinline__ unsigned int cvt_pk_bf16(float a, float b) {
    unsigned int r;
    asm("v_cvt_pk_bf16_f32 %0, %1, %2" : "=v"(r) : "v"(a), "v"(b));
    return r;
}

// async global->LDS 16B: no VGPR round-trip, loads issue back-to-back.
__device__ __forceinline__ void load_lds16(const unsigned short* g, unsigned short* l) {
    __builtin_amdgcn_global_load_lds(
        (const __attribute__((address_space(1))) unsigned int*)(g),
        (__attribute__((address_space(3))) unsigned int*)(l), 16, 0, 0);
}

typedef __attribute__((ext_vector_type(8))) short bf16x8;
typedef __attribute__((ext_vector_type(4))) float f32x4;
typedef __attribute__((ext_vector_type(2))) float floatx2;

// ---------------- BN ----------------
__global__ void bn_partial(const float* __restrict__ x, int N, int C,
                           float* __restrict__ partial) {
    int ch = threadIdx.x;            // blockDim = 128, C <= 128
    if (ch >= C) return;
    float s = 0.f, sq = 0.f;
    for (int n = blockIdx.x; n < N; n += gridDim.x) {
        float v = x[(size_t)n * C + ch];
        s += v; sq += v * v;
    }
    partial[(size_t)blockIdx.x * 2 * C + ch]     = s;
    partial[(size_t)blockIdx.x * 2 * C + C + ch] = sq;
}

// fused finalize + apply. NB is COMPILE-TIME (r27 fix: runtime nb defeated
// unrolling -> 82us latency-chain prologue; template NB restores ILP).
template <int CIN, int CP, int NB>
__global__ __launch_bounds__(256) void bn_apply_f(const float* __restrict__ x,
                                                  const float* __restrict__ partial,
                                                  const float* __restrict__ g,
                                                  const float* __restrict__ be,
                                                  float* __restrict__ scale_g,
                                                  float* __restrict__ shift_g,
                                                  unsigned short* __restrict__ xbn) {
    __shared__ float hs[2][128], hq[2][128];
    __shared__ float sc_l[CP], sh_l[CP];
    const int tid = threadIdx.x;
    const int half = tid >> 7, ch = tid & 127;
    if (ch < CIN) {
        constexpr int H = NB / 2;
        int b0 = half ? H : 0;
        int b1 = half ? NB : H;
        float s = 0.f, sq = 0.f;
#pragma unroll 8
        for (int b = b0; b < b1; ++b) {
            s  += partial[(size_t)b * 2 * CIN + ch];
            sq += partial[(size_t)b * 2 * CIN + CIN + ch];
        }
        hs[half][ch] = s; hq[half][ch] = sq;
    }
    __syncthreads();
    if (tid < CP) {
        float sc = 0.f, sh = 0.f;
        if (tid < CIN) {
            float s  = hs[0][tid] + hs[1][tid];
            float sq = hq[0][tid] + hq[1][tid];
            float mean = s / (float)NN;
            float var  = sq / (float)NN - mean * mean;
            float inv  = rsqrtf(var + 1e-5f);
            sc = g[tid] * inv;
            sh = be[tid] - mean * sc;
            if (blockIdx.x == 0) { scale_g[tid] = sc; shift_g[tid] = sh; }
        }
        sc_l[tid] = sc; sh_l[tid] = sh;
    }
    __syncthreads();
    const int total = NN * (CP / 2);
    for (int idx = blockIdx.x * 256 + tid; idx < total; idx += 256 * gridDim.x) {
        int n = idx / (CP / 2), c2 = idx % (CP / 2);
        int c = 2 * c2;
        float v0 = 0.f, v1 = 0.f;
        if (c < CIN)     v0 = sc_l[c] * x[(size_t)n * CIN + c] + sh_l[c];
        if (c + 1 < CIN) v1 = sc_l[c + 1] * x[(size_t)n * CIN + c + 1] + sh_l[c + 1];
        reinterpret_cast<unsigned int*>(xbn)[idx] = cvt_pk_bf16(v0, v1);
    }
}

// ---------------- fused weight prep for ALL layers in ONE dispatch (r20) ----------
struct PrepLayer {
    const float* W; const float* as_; const float* ad_;
    float* Wf; unsigned short* Wft; unsigned short* Wt;
    int CIN, CP, COUT, NP, bbase;
};
struct PrepArgs { PrepLayer L[4]; int nb; };

__global__ void prep_all(PrepArgs A) {
    int bid = blockIdx.x;
    int li = 0;
#pragma unroll
    for (int i = 1; i < 4; ++i)
        if (bid >= A.L[i].bbase) li = i;
    const PrepLayer& P = A.L[li];
    const int CIN = P.CIN, CP = P.CP, COUT = P.COUT;
    int b = bid - P.bbase;
    int tid = threadIdx.x;
    if (b < CP) {
        int cin = b;
        if (tid < 64) {
            int j = tid, h = j & 31;
            float s = 0.f;
            if (cin < CIN) {
                const float* a = (j < 32) ? P.as_ : P.ad_;
                const float* wrow = P.W + (size_t)cin * 32 * COUT + (size_t)h * COUT;
                const float* arow = a + (size_t)h * COUT;
                for (int c = 0; c < COUT; ++c) s += wrow[c] * arow[c];
            }
            P.Wf[cin * 64 + j] = s;
            P.Wft[j * CP + cin] = f2bf(s);
        }
    } else {
        int c = b - CP;   // [0, NP)
        for (int kk = tid; kk < 32 * CP; kk += blockDim.x) {
            int h = kk / CP, k = kk % CP;
            float v = 0.f;
            if (k < CIN && c < COUT)
                v = P.W[(size_t)k * (32 * COUT) + h * COUT + c] * (1.f / 32.f);
            P.Wt[(size_t)c * (32 * CP) + kk] = f2bf(v);
        }
    }
}

// ---------------- MFMA score GEMM: Sbuf[n, 0:64] = xbn[n,:] @ Wft^T ------------------
template <int CPK>
__global__ __launch_bounds__(256) void gemm_s(const unsigned short* __restrict__ xbn,
                                              const unsigned short* __restrict__ Wft,
                                              float* __restrict__ Sbuf) {
    constexpr int NC = CPK / 32;
    __shared__ unsigned short Ab[64 * 32];
    __shared__ unsigned short Bb[64 * 32];
    const int m0 = blockIdx.x * 64;
    const int tid = threadIdx.x;
    const int wv = tid >> 6, lane = tid & 63;
    const int mm = lane & 15, quad = lane >> 4;
    f32x4 acc[4];
#pragma unroll
    for (int t = 0; t < 4; ++t) acc[t] = f32x4{0.f, 0.f, 0.f, 0.f};

    for (int c = 0; c < NC; ++c) {
        int row = tid >> 2, gc = tid & 3;
        load_lds16(xbn + (size_t)(m0 + row) * CPK + c * 32 + gc * 8, Ab + (size_t)tid * 8);
        load_lds16(Wft + (size_t)row * CPK + c * 32 + gc * 8, Bb + (size_t)tid * 8);
        asm volatile("s_waitcnt vmcnt(0)" ::: "memory");
        __syncthreads();
        bf16x8 a = *reinterpret_cast<const bf16x8*>(&Ab[(wv * 16 + mm) * 32 + quad * 8]);
#pragma unroll
        for (int t = 0; t < 4; ++t) {
            bf16x8 b = *reinterpret_cast<const bf16x8*>(&Bb[(t * 16 + mm) * 32 + quad * 8]);
            acc[t] = __builtin_amdgcn_mfma_f32_16x16x32_bf16(a, b, acc[t], 0, 0, 0);
        }
        __syncthreads();
    }
    int rbase = m0 + wv * 16 + quad * 4;
#pragma unroll
    for (int t = 0; t < 4; ++t)
#pragma unroll
        for (int r = 0; r < 4; ++r)
            Sbuf[(size_t)(rbase + r) * 64 + t * 16 + mm] = acc[t][r];
}

// ---------------- fp32 GEMM with fused BN on A (score GEMM for small-K layers) ----
__global__ __launch_bounds__(256) void gemm_bn(const float* __restrict__ X,
                                               const float* __restrict__ W,
                                               const float* __restrict__ scale,
                                               const float* __restrict__ shift,
                                               int Cin, int HC, float* __restrict__ OUT) {
    __shared__ float As[8][64];
    __shared__ float Bs[8][64];
    int tid = threadIdx.x;
    int n0 = blockIdx.y * 64;
    int j0 = blockIdx.x * 64;
    int tr = tid >> 4, tc = tid & 15;
    float acc[4][4] = {};
    for (int k0 = 0; k0 < Cin; k0 += 8) {
        int idx = tid;
#pragma unroll
        for (int it = 0; it < 2; ++it, idx += 256) {
            int row = idx >> 3, kk = idx & 7;
            int k = k0 + kk;
            float v = 0.f;
            if (k < Cin) v = scale[k] * X[(size_t)(n0 + row) * Cin + k] + shift[k];
            As[kk][row] = v;
        }
        int idx2 = tid;
#pragma unroll
        for (int it = 0; it < 2; ++it, idx2 += 256) {
            int col = idx2 & 63, kr = idx2 >> 6;
            int k = k0 + kr, j = j0 + col;
            float v = 0.f;
            if (k < Cin && j < HC) v = W[(size_t)k * HC + j];
            Bs[kr][col] = v;
        }
        __syncthreads();
#pragma unroll
        for (int kk = 0; kk < 8; ++kk) {
            float a[4], b[4];
#pragma unroll
            for (int i = 0; i < 4; ++i) a[i] = As[kk][tr * 4 + i];
#pragma unroll
            for (int j = 0; j < 4; ++j) b[j] = Bs[kk][tc * 4 + j];
#pragma unroll
            for (int i = 0; i < 4; ++i)
#pragma unroll
                for (int j = 0; j < 4; ++j) acc[i][j] += a[i] * b[j];
        }
        __syncthreads();
    }
#pragma unroll
    for (int i = 0; i < 4; ++i) {
        int row = n0 + tr * 4 + i;
#pragma unroll
        for (int j = 0; j < 4; ++j) {
            int col = j0 + tc * 4 + j;
            if (col < HC) OUT[(size_t)row * HC + col] = acc[i][j];
        }
    }
}

// ---------------- CSR build (hierarchical 3-pass scan) ----------------
__global__ void count_kernel(const int* __restrict__ dst, int* __restrict__ deg) {
    int e = blockIdx.x * blockDim.x + threadIdx.x;
    if (e < NE) atomicAdd(&deg[dst[e]], 1);
}
__global__ void scan_pass1(const int* __restrict__ deg, int* __restrict__ bsum) {
    __shared__ int red[256];
    int b = blockIdx.x, t = threadIdx.x;
    int lo = b * SCHUNK, hi = min(lo + SCHUNK, NN);
    int s = 0;
    for (int i = lo + t; i < hi; i += 256) s += deg[i] + 1;   // +1 self-loop
    red[t] = s;
    __syncthreads();
    for (int off = 128; off > 0; off >>= 1) {
        if (t < off) red[t] += red[t + off];
        __syncthreads();
    }
    if (t == 0) bsum[b] = red[0];
}
__global__ void scan_pass2(const int* __restrict__ bsum, int* __restrict__ boff,
                           int* __restrict__ rowptr) {
    __shared__ int lds[256];
    int t = threadIdx.x;
    int v0 = bsum[t];
    lds[t] = v0;
    __syncthreads();
    for (int off = 1; off < 256; off <<= 1) {
        int v = (t >= off) ? lds[t - off] : 0;
        __syncthreads();
        lds[t] += v;
        __syncthreads();
    }
    boff[t] = lds[t] - v0;          // exclusive
    if (t == 255) rowptr[NN] = lds[255];
}
__global__ void scan_pass3(const int* __restrict__ deg, const int* __restrict__ boff,
                           int* __restrict__ rowptr, int* __restrict__ cursor) {
    __shared__ int lds[256];
    int b = blockIdx.x, t = threadIdx.x;
    int i = b * SCHUNK + t;
    int d = (t < SCHUNK && i < NN) ? (deg[i] + 1) : 0;   // +1 self-loop
    lds[t] = d;
    __syncthreads();
    for (int off = 1; off < 256; off <<= 1) {
        int v = (t >= off) ? lds[t - off] : 0;
        __syncthreads();
        lds[t] += v;
        __syncthreads();
    }
    if (t < SCHUNK && i < NN) {
        int excl = lds[t] - d + boff[b];
        rowptr[i] = excl;
        cursor[i] = excl;
    }
}
__global__ void scatter_all(const int* __restrict__ src, const int* __restrict__ dst,
                            int* __restrict__ cursor, int* __restrict__ colsrc) {
    int e = blockIdx.x * blockDim.x + threadIdx.x;
    if (e < NE) {
        int pos = atomicAdd(&cursor[dst[e]], 1);
        colsrc[pos] = src[e];
    } else if (e < NE + NN) {
        int n = e - NE;
        int pos = atomicAdd(&cursor[n], 1);
        colsrc[pos] = n;
    }
}

// ---------------- pass A: softmax-aggregate xbn -> z[n, 32*CP] (bf16) ----------------
// Proven r21 form (block-per-node, CH=16, direct uint2 stores, conflicts 0).
template <int CIN, int CP>
__global__ __launch_bounds__(256) void agg_x(const unsigned short* __restrict__ xbn,
                                             const float* __restrict__ S,
                                             const int* __restrict__ rowptr,
                                             const int* __restrict__ colsrc,
                                             int n0, unsigned short* __restrict__ z) {
    constexpr int BS = 256, CH = 16, J = CP / 8;   // J = 16,12,6,2
    constexpr bool V4 = (J % 4 == 0);
    constexpr int NACC = V4 ? (J / 4) : (J / 2);
    constexpr int LIT = CH * 32 / 256;             // 2 logit iterations
    __shared__ __align__(16) float x_lds[CH * CP];
    __shared__ float w_lds[CH * 32];
    __shared__ int cs_lds[CH];
    __shared__ float red_m[8][32];
    __shared__ float red_s[8][32];

    int n = n0 + blockIdx.x;
    int tid = threadIdx.x;
    int start = rowptr[n], end = rowptr[n + 1];
    const int h = tid & 31, g = tid >> 5;
    const int cbase = g * J;
    const float sd = S[(size_t)n * 64 + 32 + h];   // broadcast within head column

    float m_reg = -INFINITY, d_reg = 0.f;
    f32x4 acc4[V4 ? NACC : 1];
    floatx2 acc2[V4 ? 1 : NACC];
    if constexpr (V4) {
#pragma unroll
        for (int j = 0; j < NACC; ++j) acc4[j] = f32x4{0.f, 0.f, 0.f, 0.f};
    } else {
#pragma unroll
        for (int j = 0; j < NACC; ++j) acc2[j] = floatx2{0.f, 0.f};
    }

    for (int chunk = start; chunk < end; chunk += CH) {
        int ce = min(CH, end - chunk);
        int ce32 = ce * 32;
        if (tid < CH && tid < ce) cs_lds[tid] = colsrc[chunk + tid];
        __syncthreads();   // B1: cs_lds visible

        float lreg[LIT];
        float pmx = -INFINITY;
#pragma unroll
        for (int p = 0; p < LIT; ++p) {
            int idx = p * 256 + tid;
            lreg[p] = -INFINITY;
            if (idx < ce32) {
                int e = idx >> 5;
                float l = S[(size_t)cs_lds[e] * 64 + h] + sd;
                l = l > 0.f ? l : 0.2f * l;
                lreg[p] = l;
                pmx = fmaxf(pmx, l);
            }
        }
        red_m[g][h] = pmx;
        // stage x rows (bf16 -> f32) via uint2, f32x4 stores
        for (int idx = tid; idx < ce * (CP / 4); idx += BS) {
            int e = idx / (CP / 4), c4 = idx % (CP / 4);
            uint2 u = reinterpret_cast<const uint2*>(xbn)[(size_t)cs_lds[e] * (CP / 4) + c4];
            f32x4 t;
            t[0] = __uint_as_float(u.x << 16);
            t[1] = __uint_as_float(u.x & 0xFFFF0000u);
            t[2] = __uint_as_float(u.y << 16);
            t[3] = __uint_as_float(u.y & 0xFFFF0000u);
            *reinterpret_cast<f32x4*>(&x_lds[e * CP + 4 * c4]) = t;
        }
        __syncthreads();   // B2: red_m + x_lds visible

        // per-thread redundant max reduce (identical order to serial version)
        float cm = red_m[0][h];
#pragma unroll
        for (int s2 = 1; s2 < 8; ++s2) cm = fmaxf(cm, red_m[s2][h]);
        float newm = fmaxf(m_reg, cm);
        float r = (m_reg == -INFINITY) ? 0.f : __expf(m_reg - newm);
        m_reg = newm;

        float ps = 0.f;
#pragma unroll
        for (int p = 0; p < LIT; ++p) {
            int idx = p * 256 + tid;
            if (idx < ce32) {
                float v = __expf(lreg[p] - m_reg);
                w_lds[idx] = v;
                ps += v;
            }
        }
        red_s[g][h] = ps;
        __syncthreads();   // B3: w_lds + red_s visible

        float ss = red_s[0][h];
#pragma unroll
        for (int s2 = 1; s2 < 8; ++s2) ss += red_s[s2][h];
        d_reg = d_reg * r + ss;

        if constexpr (V4) {
            f32x4 rr4 = {r, r, r, r};
#pragma unroll
            for (int j = 0; j < NACC; ++j) acc4[j] *= rr4;
            for (int e = 0; e < ce; ++e) {
                float w = w_lds[e * 32 + h];
                f32x4 w4 = {w, w, w, w};
                const f32x4* xv = reinterpret_cast<const f32x4*>(&x_lds[e * CP + cbase]);
#pragma unroll
                for (int j = 0; j < NACC; ++j) acc4[j] += w4 * xv[j];
            }
        } else {
            floatx2 rr2 = {r, r};
#pragma unroll
            for (int j = 0; j < NACC; ++j) acc2[j] *= rr2;
            for (int e = 0; e < ce; ++e) {
                float w = w_lds[e * 32 + h];
                floatx2 w2 = {w, w};
                const floatx2* xv = reinterpret_cast<const floatx2*>(&x_lds[e * CP + cbase]);
#pragma unroll
                for (int j = 0; j < NACC; ++j) acc2[j] += w2 * xv[j];
            }
        }
    }

    float dinv = 1.f / d_reg;
    if constexpr (V4) {
        uint2* zp = reinterpret_cast<uint2*>(
            z + (size_t)(n - n0) * (32 * CP) + h * CP + cbase);
#pragma unroll
        for (int j = 0; j < NACC; ++j) {
            uint2 t;
            t.x = cvt_pk_bf16(acc4[j][0] * dinv, acc4[j][1] * dinv);
            t.y = cvt_pk_bf16(acc4[j][2] * dinv, acc4[j][3] * dinv);
            zp[j] = t;
        }
    } else {
        unsigned int* zp = reinterpret_cast<unsigned int*>(
            z + (size_t)(n - n0) * (32 * CP) + h * CP + cbase);
#pragma unroll
        for (int j = 0; j < NACC; ++j)
            zp[j] = cvt_pk_bf16(acc2[j][0] * dinv, acc2[j][1] * dinv);
    }
}

// ---------------- pass B: LDS-tiled MFMA GEMM (MT=64) ----------------
// runtime nr (row count) + pstride (pbuf part stride, rows). FB path optionally
// emits per-channel BN stat partials (NT==1) via a deterministic LDS tree.
template <int NT, int KP, int KS, bool FB, bool STATS>
__global__ __launch_bounds__(256) void gemm_z_t(const unsigned short* __restrict__ z,
                                                const unsigned short* __restrict__ Wt,
                                                float* __restrict__ obuf,
                                                const float* __restrict__ bias,
                                                int n0, int COUT, int nr, int pstride,
                                                float* __restrict__ statp) {
    constexpr int NP = NT * 16;
    constexpr int KSEG = KP / KS;       // multiple of 64
    constexpr int NC = KSEG / 64;
    constexpr int MT = 64;
    __shared__ unsigned short Abuf[2][MT * 64];
    __shared__ unsigned short Bbuf[2][NP * 64];

    const int m0 = blockIdx.x * MT;
    const int kbeg = blockIdx.y * KSEG;
    const int tid = threadIdx.x;
    const int wv = tid >> 6;
    const int lane = tid & 63;
    const int mm = lane & 15, quad = lane >> 4;

    auto stage = [&](int buf, int kk) {
#pragma unroll
        for (int it = 0; it < 2; ++it) {
            int gi = it * 256 + tid;
            int row = gi >> 3, gc = gi & 7;
            int srow = m0 + row;
            if (srow > nr - 1) srow = nr - 1;
            const unsigned short* src = z + (size_t)srow * KP + kk + gc * 8;
            unsigned short* dst = &Abuf[buf][(size_t)(it * 256 + wv * 64) * 8];
            load_lds16(src, dst);
        }
#pragma unroll
        for (int it = 0; it < (NP * 8 + 255) / 256; ++it) {
            int gi = it * 256 + tid;
            if (gi < NP * 8) {
                int row = gi >> 3, gc = gi & 7;
                const unsigned short* src = Wt + (size_t)row * KP + kk + gc * 8;
                unsigned short* dst = &Bbuf[buf][(size_t)(it * 256 + wv * 64) * 8];
                load_lds16(src, dst);
            }
        }
    };

    f32x4 acc[NT];
#pragma unroll
    for (int t = 0; t < NT; ++t) acc[t] = f32x4{0.f, 0.f, 0.f, 0.f};

    stage(0, kbeg);
    for (int c = 0; c < NC; ++c) {
        asm volatile("s_waitcnt vmcnt(0)" ::: "memory");
        __syncthreads();
        int cur = c & 1;
        if (c + 1 < NC) stage(cur ^ 1, kbeg + (c + 1) * 64);
        const unsigned short* Ab = Abuf[cur];
        const unsigned short* Bb = Bbuf[cur];
#pragma unroll
        for (int hh = 0; hh < 2; ++hh) {
            bf16x8 a0 = *reinterpret_cast<const bf16x8*>(&Ab[(wv * 16 + mm) * 64 + hh * 32 + quad * 8]);
#pragma unroll
            for (int t = 0; t < NT; ++t) {
                bf16x8 b = *reinterpret_cast<const bf16x8*>(&Bb[(t * 16 + mm) * 64 + hh * 32 + quad * 8]);
                acc[t] = __builtin_amdgcn_mfma_f32_16x16x32_bf16(a0, b, acc[t], 0, 0, 0);
            }
        }
        __syncthreads();
    }

    int row0 = quad * 4;
    if constexpr (FB) {
        float s = 0.f, q = 0.f;
#pragma unroll
        for (int t = 0; t < NT; ++t) {
            int cc = t * 16 + mm;
#pragma unroll
            for (int r = 0; r < 4; ++r) {
                int m = m0 + wv * 16 + row0 + r;
                if (m < nr && cc < COUT) {
                    float v = acc[t][r] + bias[cc];
                    v = v > 0.f ? v : 0.01f * v;
                    obuf[(size_t)(n0 + m) * COUT + cc] = v;
                    if constexpr (STATS) { s += v; q += v * v; }
                }
            }
        }
        if constexpr (STATS) {
            static_assert(NT == 1, "STATS path assumes NT==1");
            __shared__ float ssum[4][4][16], sqsum[4][4][16];
            ssum[wv][quad][mm] = s; sqsum[wv][quad][mm] = q;
            __syncthreads();
            if (tid < 16) {
                float S = 0.f, Q = 0.f;
#pragma unroll
                for (int a = 0; a < 4; ++a)
#pragma unroll
                    for (int b2 = 0; b2 < 4; ++b2) {
                        S += ssum[a][b2][tid]; Q += sqsum[a][b2][tid];
                    }
                if (tid < COUT) {
                    statp[(size_t)blockIdx.x * 2 * COUT + tid] = S;
                    statp[(size_t)blockIdx.x * 2 * COUT + COUT + tid] = Q;
                }
            }
        }
    } else {
        float* pb = obuf + (size_t)blockIdx.y * pstride * NP;
#pragma unroll
        for (int t = 0; t < NT; ++t) {
            int cc = t * 16 + mm;
#pragma unroll
            for (int r = 0; r < 4; ++r) {
                int m = m0 + wv * 16 + row0 + r;
                pb[(size_t)m * NP + cc] = acc[t][r];
            }
        }
    }
}

// reduce K-split partials + bias + leaky 0.01 -> xout (fully-parallel form;
// runtime nr rows + pstride part stride)
__global__ void reduce_parts(const float* __restrict__ pbuf, int KS, int NPAD, int COUT,
                             const float* __restrict__ bias, int n0, int nr, int pstride,
                             float* __restrict__ xout) {
    int idx = blockIdx.x * blockDim.x + threadIdx.x;
    if (idx >= nr * NPAD) return;
    int m = idx / NPAD, c = idx % NPAD;
    if (c >= COUT) return;
    float s = 0.f;
    for (int p = 0; p < KS; ++p) s += pbuf[(size_t)p * pstride * NPAD + (size_t)m * NPAD + c];
    float v = s + bias[c];
    v = v > 0.f ? v : 0.01f * v;
    xout[(size_t)(n0 + m) * COUT + c] = v;
}

// ---------------- fused mean-pool + FC + sigmoid ----------------
__global__ __launch_bounds__(64) void pool_head(const float* __restrict__ x4,
                                                const int* __restrict__ batch,
                                                const float* __restrict__ cond,
                                                const float* __restrict__ fcW,
                                                const float* __restrict__ fcb,
                                                float* __restrict__ out) {
    int g = blockIdx.x;
    int lane = threadIdx.x;
    int lo = 0, hi = NN;
    while (lo < hi) { int mid = (lo + hi) >> 1; if (batch[mid] < g) lo = mid + 1; else hi = mid; }
    int lo2 = lo, hi2 = NN;
    while (lo2 < hi2) { int mid = (lo2 + hi2) >> 1; if (batch[mid] < g + 1) lo2 = mid + 1; else hi2 = mid; }
    int beg = lo, end = lo2;

    float s[5] = {0.f, 0.f, 0.f, 0.f, 0.f};
    for (int n = beg + lane; n < end; n += 64) {
#pragma unroll
        for (int c = 0; c < 5; ++c) s[c] += x4[(size_t)n * 5 + c];
    }
    float cz = 0.f;
    if (lane < 100) cz = cond[lane] * fcW[5 + lane];
    if (lane + 64 < 100) cz += cond[lane + 64] * fcW[5 + lane + 64];
#pragma unroll
    for (int off = 32; off > 0; off >>= 1) {
#pragma unroll
        for (int c = 0; c < 5; ++c) s[c] += __shfl_down(s[c], off, 64);
        cz += __shfl_down(cz, off, 64);
    }
    if (lane == 0) {
        float cnt = fmaxf((float)(end - beg), 1.f);
        float zv = fcb[0] + cz;
#pragma unroll
        for (int c = 0; c < 5; ++c) zv += (s[c] / cnt) * fcW[c];
        out[g] = 1.f / (1.f + __expf(-zv));
    }
}

// ---------------- per-layer driver ----------------
struct LayerBufs {
    float* scale; float* shift;
    unsigned short* xbn; unsigned short* zbuf;
    float* Sbuf; float* pbuf; const int* rowptr; const int* colsrc;
};

template <int CIN, int CP, int COUT, int NP, int NT, int KS, int SLABS, int NB, bool OSTATS>
static void run_layer(const float* xin, const float* sp_in,
                      const float* Wf, const unsigned short* Wft,
                      const unsigned short* Wt,
                      const float* Bv, const float* G, const float* Be,
                      float* xout, float* statp, int pstride,
                      const LayerBufs& B, hipStream_t stream) {
    constexpr int KP = 32 * CP;
    constexpr int NPAD = NT * 16;
    constexpr int NR = NN / SLABS;
    constexpr int NTILE = (NR + 63) / 64;
    bn_apply_f<CIN, CP, NB><<<512, 256, 0, stream>>>(xin, sp_in, G, Be,
                                                     B.scale, B.shift, B.xbn);
    if constexpr (CP >= 64) {
        gemm_s<CP><<<NN / 64, 256, 0, stream>>>(B.xbn, Wft, B.Sbuf);
    } else {
        gemm_bn<<<dim3(1, NN / 64), 256, 0, stream>>>(xin, Wf, B.scale, B.shift, CIN, 64, B.Sbuf);
    }
    for (int s = 0; s < SLABS; ++s) {
        int n0 = s * NR;
        agg_x<CIN, CP><<<NR, 256, 0, stream>>>(B.xbn, B.Sbuf, B.rowptr, B.colsrc, n0, B.zbuf);
        if constexpr (KS > 1) {
            gemm_z_t<NT, KP, KS, false, false><<<dim3(NTILE, KS), 256, 0, stream>>>(
                B.zbuf, Wt, B.pbuf, nullptr, n0, COUT, NR, pstride, nullptr);
            reduce_parts<<<((size_t)NR * NPAD + 255) / 256, 256, 0, stream>>>(
                B.pbuf, KS, NPAD, COUT, Bv, n0, NR, pstride, xout);
        } else {
            gemm_z_t<NT, KP, 1, true, OSTATS><<<dim3(NTILE, 1), 256, 0, stream>>>(
                B.zbuf, Wt, xout, Bv, n0, COUT, NR, pstride, statp);
        }
    }
}

extern "C" void kernel_launch(void* const* d_in, const int* in_sizes, int n_in,
                              void* d_out, int out_size, void* d_ws, size_t ws_size,
                              hipStream_t stream) {
    (void)in_sizes; (void)n_in; (void)out_size;
    const float* x     = (const float*)d_in[0];
    const int*   ei    = (const int*)d_in[1];
    const int*   batch = (const int*)d_in[2];
    const float* cond  = (const float*)d_in[3];
    const float* W[4]  = {(const float*)d_in[4],  (const float*)d_in[8],
                          (const float*)d_in[12], (const float*)d_in[16]};
    const float* Asp[4] = {(const float*)d_in[5],  (const float*)d_in[9],
                           (const float*)d_in[13], (const float*)d_in[17]};
    const float* Adp[4] = {(const float*)d_in[6],  (const float*)d_in[10],
                           (const float*)d_in[14], (const float*)d_in[18]};
    const float* Bv[4]  = {(const float*)d_in[7],  (const float*)d_in[11],
                           (const float*)d_in[15], (const float*)d_in[19]};
    const float* G[4]   = {(const float*)d_in[20], (const float*)d_in[22],
                           (const float*)d_in[24], (const float*)d_in[26]};
    const float* Be[4]  = {(const float*)d_in[21], (const float*)d_in[23],
                           (const float*)d_in[25], (const float*)d_in[27]};
    const float* fcW = (const float*)d_in[30];
    const float* fcb = (const float*)d_in[31];
    float* out = (float*)d_out;

    const int CPs[4]  = {128, 96, 48, 16};
    const int NPs[4]  = {96, 48, 16, 16};
    const int CINs[4] = {128, 90, 45, 15};
    const int COUTs[4] = {90, 45, 15, 5};

    // r28: runtime choice — single-slab L1/L2 (zbuf 40K rows, 328MB) when
    // ws_size permits; else the proven 2-slab fallback (r27 behavior).
    auto layout_total = [&](size_t zb, size_t pb) -> size_t {
        size_t o = 0;
        auto a = [&](size_t b) { o += (b + 255) & ~(size_t)255; };
        a(zb); a((size_t)NN * 128 * 2); a(pb); a((size_t)NN * 90 * 4);
        a((size_t)NN * 64 * 4); a((size_t)NPB * 2 * 128 * 4); a((size_t)NPB * 2 * 128 * 4);
        a(128 * 4); a(128 * 4);
        for (int i = 0; i < 4; ++i) {
            a((size_t)CPs[i] * 64 * 4); a((size_t)64 * CPs[i] * 2);
            a((size_t)NPs[i] * 32 * CPs[i] * 2);
        }
        a((size_t)NN * 4); a((size_t)(NN + 1) * 4); a((size_t)NN * 4);
        a((size_t)(NE + NN) * 4); a((size_t)SCB * 4); a((size_t)SCB * 4);
        return o;
    };
    const size_t zb_big = (size_t)NN * 4096 * 2, pb_big = (size_t)4 * MPADX * 96 * 4;
    const size_t zb_sm  = (size_t)NSLAB * 4096 * 2, pb_sm = (size_t)4 * MPAD * 96 * 4;
    const bool big = layout_total(zb_big, pb_big) <= ws_size;
    const size_t zb = big ? zb_big : zb_sm;
    const size_t pbb = big ? pb_big : pb_sm;
    const int pstride = big ? MPADX : MPAD;

    char* base = (char*)d_ws;
    size_t off = 0;
    auto alloc = [&](size_t b) {
        size_t o = off;
        off += (b + 255) & ~(size_t)255;
        return (void*)(base + o);
    };
    unsigned short* zbuf = (unsigned short*)alloc(zb);
    unsigned short* xbn  = (unsigned short*)alloc((size_t)NN * 128 * 2);
    float* pbuf    = (float*)alloc(pbb);
    float* xbuf    = (float*)alloc((size_t)NN * 90 * 4);
    float* Sbuf    = (float*)alloc((size_t)NN * 64 * 4);
    float* partial = (float*)alloc((size_t)NPB * 2 * 128 * 4);
    float* stat1   = (float*)alloc((size_t)NPB * 2 * 128 * 4);
    float* scale   = (float*)alloc(128 * 4);
    float* shift   = (float*)alloc(128 * 4);
    float* Wf_a[4]; unsigned short* Wft_a[4]; unsigned short* Wt_a[4];
    for (int i = 0; i < 4; ++i) {
        Wf_a[i]  = (float*)alloc((size_t)CPs[i] * 64 * 4);
        Wft_a[i] = (unsigned short*)alloc((size_t)64 * CPs[i] * 2);
        Wt_a[i]  = (unsigned short*)alloc((size_t)NPs[i] * 32 * CPs[i] * 2);
    }
    int* deg     = (int*)alloc((size_t)NN * 4);
    int* rowptr  = (int*)alloc((size_t)(NN + 1) * 4);
    int* cursor  = (int*)alloc((size_t)NN * 4);
    int* colsrc  = (int*)alloc((size_t)(NE + NN) * 4);
    int* bsum    = (int*)alloc((size_t)SCB * 4);
    int* boff    = (int*)alloc((size_t)SCB * 4);
    if (off > ws_size) return;

    const int* srcp = ei;
    const int* dstp = ei + NE;

    // all-layer weight prep in one dispatch, first (independent of everything)
    PrepArgs PA;
    int bb = 0;
    for (int i = 0; i < 4; ++i) {
        PA.L[i] = PrepLayer{W[i], Asp[i], Adp[i], Wf_a[i], Wft_a[i], Wt_a[i],
                            CINs[i], CPs[i], COUTs[i], NPs[i], bb};
        bb += CPs[i] + NPs[i];
    }
    PA.nb = bb;
    prep_all<<<bb, 256, 0, stream>>>(PA);

    // CSR by dst (hierarchical scan); deg zeroed via memset, self-loop +1 in scans
    hipMemsetAsync(deg, 0, (size_t)NN * 4, stream);
    count_kernel<<<(NE + 255) / 256, 256, 0, stream>>>(dstp, deg);
    scan_pass1<<<SCB, 256, 0, stream>>>(deg, bsum);
    scan_pass2<<<1, 256, 0, stream>>>(bsum, boff, rowptr);
    scan_pass3<<<SCB, 256, 0, stream>>>(deg, boff, rowptr, cursor);
    scatter_all<<<(NE + NN + 255) / 256, 256, 0, stream>>>(srcp, dstp, cursor, colsrc);

    LayerBufs B{scale, shift, xbn, zbuf, Sbuf, pbuf, rowptr, colsrc};

    if (big) {
        bn_partial<<<NPB, 128, 0, stream>>>(x, NN, 128, partial);
        run_layer<128, 128, 90, 96, 6, 4, 1, NPB, false>(x, partial,
            Wf_a[0], Wft_a[0], Wt_a[0], Bv[0], G[0], Be[0], xbuf, nullptr, pstride, B, stream);
        bn_partial<<<NPB, 128, 0, stream>>>(xbuf, NN, 90, partial);
        run_layer< 90,  96, 45, 48, 3, 3, 1, NPB, false>(xbuf, partial,
            Wf_a[1], Wft_a[1], Wt_a[1], Bv[1], G[1], Be[1], xbuf, nullptr, pstride, B, stream);
        bn_partial<<<NPB, 128, 0, stream>>>(xbuf, NN, 45, partial);
        run_layer< 45,  48, 15, 16, 1, 1, 1, NPB, true >(xbuf, partial,
            Wf_a[2], Wft_a[2], Wt_a[2], Bv[2], G[2], Be[2], xbuf, stat1, pstride, B, stream);
        run_layer< 15,  16,  5, 16, 1, 1, 1, 625, false>(xbuf, stat1,
            Wf_a[3], Wft_a[3], Wt_a[3], Bv[3], G[3], Be[3], xbuf, nullptr, pstride, B, stream);
    } else {
        bn_partial<<<NPB, 128, 0, stream>>>(x, NN, 128, partial);
        run_layer<128, 128, 90, 96, 6, 4, 2, NPB, false>(x, partial,
            Wf_a[0], Wft_a[0], Wt_a[0], Bv[0], G[0], Be[0], xbuf, nullptr, pstride, B, stream);
        bn_partial<<<NPB, 128, 0, stream>>>(xbuf, NN, 90, partial);
        run_layer< 90,  96, 45, 48, 3, 3, 2, NPB, false>(xbuf, partial,
            Wf_a[1], Wft_a[1], Wt_a[1], Bv[1], G[1], Be[1], xbuf, nullptr, pstride, B, stream);
        bn_partial<<<NPB, 128, 0, stream>>>(xbuf, NN, 45, partial);
        run_layer< 45,  48, 15, 16, 1, 1, 1, NPB, true >(xbuf, partial,
            Wf_a[2], Wft_a[2], Wt_a[2], Bv[2], G[2], Be[2], xbuf, stat1, pstride, B, stream);
        run_layer< 15,  16,  5, 16, 1, 1, 1, 625, false>(xbuf, stat1,
            Wf_a[3], Wft_a[3], Wt_a[3], Bv[3], G[3], Be[3], xbuf, nullptr, pstride, B, stream);
    }

    pool_head<<<256, 64, 0, stream>>>(xbuf, batch, cond, fcW, fcb, out);
}

// Round 15
// 937.834 us; speedup vs baseline: 1.5377x; 1.0140x over previous
//
#include <hip/hip_runtime.h>
#include <hip/hip_bf16.h>

// ---------------- constants ----------------
constexpr int NN = 40000;   // nodes
constexpr int NE = 400000;  // edges (before self-loops)
constexpr int NSLAB = 20000;
constexpr int MPAD = 20096; // 314 * 64 (2-slab M-tile overrun padding)
constexpr int MPADX = 40192; // part stride (rows) covering single-slab mode
constexpr int SCB = 256;    // scan blocks
constexpr int SCHUNK = (NN + SCB - 1) / SCB;   // 157 (<= 256)
constexpr int NPB = 512;    // bn_partial blocks (rows of `partial`)

__device__ __forceinline__ unsigned short f2bf(float f) {
    unsigned int u = __float_as_uint(f);
    unsigned int r = (u + 0x7FFFu + ((u >> 16) & 1u)) >> 16;
    return (unsigned short)r;
}

// packed f32x2 -> bf16x2, RTNE (bit-identical to f2bf pairs), 1 instruction
__device__ __forceinline__ unsigned int cvt_pk_bf16(float a, float b) {
    unsigned int r;
    asm("v_cvt_pk_bf16_f32 %0, %1, %2" : "=v"(r) : "v"(a), "v"(b));
    return r;
}

// async global->LDS 16B: no VGPR round-trip, loads issue back-to-back.
__device__ __forceinline__ void load_lds16(const unsigned short* g, unsigned short* l) {
    __builtin_amdgcn_global_load_lds(
        (const __attribute__((address_space(1))) unsigned int*)(g),
        (__attribute__((address_space(3))) unsigned int*)(l), 16, 0, 0);
}

typedef __attribute__((ext_vector_type(8))) short bf16x8;
typedef __attribute__((ext_vector_type(4))) float f32x4;

// ---------------- BN ----------------
__global__ void bn_partial(const float* __restrict__ x, int N, int C,
                           float* __restrict__ partial) {
    int ch = threadIdx.x;            // blockDim = 128, C <= 128
    if (ch >= C) return;
    float s = 0.f, sq = 0.f;
    for (int n = blockIdx.x; n < N; n += gridDim.x) {
        float v = x[(size_t)n * C + ch];
        s += v; sq += v * v;
    }
    partial[(size_t)blockIdx.x * 2 * C + ch]     = s;
    partial[(size_t)blockIdx.x * 2 * C + C + ch] = sq;
}

// fused finalize + apply. NB is COMPILE-TIME (r27 fix: runtime nb defeated
// unrolling -> 82us latency-chain prologue; template NB restores ILP).
template <int CIN, int CP, int NB>
__global__ __launch_bounds__(256) void bn_apply_f(const float* __restrict__ x,
                                                  const float* __restrict__ partial,
                                                  const float* __restrict__ g,
                                                  const float* __restrict__ be,
                                                  float* __restrict__ scale_g,
                                                  float* __restrict__ shift_g,
                                                  unsigned short* __restrict__ xbn) {
    __shared__ float hs[2][128], hq[2][128];
    __shared__ float sc_l[CP], sh_l[CP];
    const int tid = threadIdx.x;
    const int half = tid >> 7, ch = tid & 127;
    if (ch < CIN) {
        constexpr int H = NB / 2;
        int b0 = half ? H : 0;
        int b1 = half ? NB : H;
        float s = 0.f, sq = 0.f;
#pragma unroll 8
        for (int b = b0; b < b1; ++b) {
            s  += partial[(size_t)b * 2 * CIN + ch];
            sq += partial[(size_t)b * 2 * CIN + CIN + ch];
        }
        hs[half][ch] = s; hq[half][ch] = sq;
    }
    __syncthreads();
    if (tid < CP) {
        float sc = 0.f, sh = 0.f;
        if (tid < CIN) {
            float s  = hs[0][tid] + hs[1][tid];
            float sq = hq[0][tid] + hq[1][tid];
            float mean = s / (float)NN;
            float var  = sq / (float)NN - mean * mean;
            float inv  = rsqrtf(var + 1e-5f);
            sc = g[tid] * inv;
            sh = be[tid] - mean * sc;
            if (blockIdx.x == 0) { scale_g[tid] = sc; shift_g[tid] = sh; }
        }
        sc_l[tid] = sc; sh_l[tid] = sh;
    }
    __syncthreads();
    const int total = NN * (CP / 2);
    for (int idx = blockIdx.x * 256 + tid; idx < total; idx += 256 * gridDim.x) {
        int n = idx / (CP / 2), c2 = idx % (CP / 2);
        int c = 2 * c2;
        float v0 = 0.f, v1 = 0.f;
        if (c < CIN)     v0 = sc_l[c] * x[(size_t)n * CIN + c] + sh_l[c];
        if (c + 1 < CIN) v1 = sc_l[c + 1] * x[(size_t)n * CIN + c + 1] + sh_l[c + 1];
        reinterpret_cast<unsigned int*>(xbn)[idx] = cvt_pk_bf16(v0, v1);
    }
}

// ---------------- fused weight prep for ALL layers in ONE dispatch (r20) ----------
struct PrepLayer {
    const float* W; const float* as_; const float* ad_;
    float* Wf; unsigned short* Wft; unsigned short* Wt;
    int CIN, CP, COUT, NP, bbase;
};
struct PrepArgs { PrepLayer L[4]; int nb; };

__global__ void prep_all(PrepArgs A) {
    int bid = blockIdx.x;
    int li = 0;
#pragma unroll
    for (int i = 1; i < 4; ++i)
        if (bid >= A.L[i].bbase) li = i;
    const PrepLayer& P = A.L[li];
    const int CIN = P.CIN, CP = P.CP, COUT = P.COUT;
    int b = bid - P.bbase;
    int tid = threadIdx.x;
    if (b < CP) {
        int cin = b;
        if (tid < 64) {
            int j = tid, h = j & 31;
            float s = 0.f;
            if (cin < CIN) {
                const float* a = (j < 32) ? P.as_ : P.ad_;
                const float* wrow = P.W + (size_t)cin * 32 * COUT + (size_t)h * COUT;
                const float* arow = a + (size_t)h * COUT;
                for (int c = 0; c < COUT; ++c) s += wrow[c] * arow[c];
            }
            P.Wf[cin * 64 + j] = s;
            P.Wft[j * CP + cin] = f2bf(s);
        }
    } else {
        int c = b - CP;   // [0, NP)
        for (int kk = tid; kk < 32 * CP; kk += blockDim.x) {
            int h = kk / CP, k = kk % CP;
            float v = 0.f;
            if (k < CIN && c < COUT)
                v = P.W[(size_t)k * (32 * COUT) + h * COUT + c] * (1.f / 32.f);
            P.Wt[(size_t)c * (32 * CP) + kk] = f2bf(v);
        }
    }
}

// ---------------- MFMA score GEMM: Sbuf[n, 0:64] = xbn[n,:] @ Wft^T ------------------
template <int CPK>
__global__ __launch_bounds__(256) void gemm_s(const unsigned short* __restrict__ xbn,
                                              const unsigned short* __restrict__ Wft,
                                              float* __restrict__ Sbuf) {
    constexpr int NC = CPK / 32;
    __shared__ unsigned short Ab[64 * 32];
    __shared__ unsigned short Bb[64 * 32];
    const int m0 = blockIdx.x * 64;
    const int tid = threadIdx.x;
    const int wv = tid >> 6, lane = tid & 63;
    const int mm = lane & 15, quad = lane >> 4;
    f32x4 acc[4];
#pragma unroll
    for (int t = 0; t < 4; ++t) acc[t] = f32x4{0.f, 0.f, 0.f, 0.f};

    for (int c = 0; c < NC; ++c) {
        int row = tid >> 2, gc = tid & 3;
        load_lds16(xbn + (size_t)(m0 + row) * CPK + c * 32 + gc * 8, Ab + (size_t)tid * 8);
        load_lds16(Wft + (size_t)row * CPK + c * 32 + gc * 8, Bb + (size_t)tid * 8);
        asm volatile("s_waitcnt vmcnt(0)" ::: "memory");
        __syncthreads();
        bf16x8 a = *reinterpret_cast<const bf16x8*>(&Ab[(wv * 16 + mm) * 32 + quad * 8]);
#pragma unroll
        for (int t = 0; t < 4; ++t) {
            bf16x8 b = *reinterpret_cast<const bf16x8*>(&Bb[(t * 16 + mm) * 32 + quad * 8]);
            acc[t] = __builtin_amdgcn_mfma_f32_16x16x32_bf16(a, b, acc[t], 0, 0, 0);
        }
        __syncthreads();
    }
    int rbase = m0 + wv * 16 + quad * 4;
#pragma unroll
    for (int t = 0; t < 4; ++t)
#pragma unroll
        for (int r = 0; r < 4; ++r)
            Sbuf[(size_t)(rbase + r) * 64 + t * 16 + mm] = acc[t][r];
}

// ---------------- fp32 GEMM with fused BN on A (score GEMM for small-K layers) ----
__global__ __launch_bounds__(256) void gemm_bn(const float* __restrict__ X,
                                               const float* __restrict__ W,
                                               const float* __restrict__ scale,
                                               const float* __restrict__ shift,
                                               int Cin, int HC, float* __restrict__ OUT) {
    __shared__ float As[8][64];
    __shared__ float Bs[8][64];
    int tid = threadIdx.x;
    int n0 = blockIdx.y * 64;
    int j0 = blockIdx.x * 64;
    int tr = tid >> 4, tc = tid & 15;
    float acc[4][4] = {};
    for (int k0 = 0; k0 < Cin; k0 += 8) {
        int idx = tid;
#pragma unroll
        for (int it = 0; it < 2; ++it, idx += 256) {
            int row = idx >> 3, kk = idx & 7;
            int k = k0 + kk;
            float v = 0.f;
            if (k < Cin) v = scale[k] * X[(size_t)(n0 + row) * Cin + k] + shift[k];
            As[kk][row] = v;
        }
        int idx2 = tid;
#pragma unroll
        for (int it = 0; it < 2; ++it, idx2 += 256) {
            int col = idx2 & 63, kr = idx2 >> 6;
            int k = k0 + kr, j = j0 + col;
            float v = 0.f;
            if (k < Cin && j < HC) v = W[(size_t)k * HC + j];
            Bs[kr][col] = v;
        }
        __syncthreads();
#pragma unroll
        for (int kk = 0; kk < 8; ++kk) {
            float a[4], b[4];
#pragma unroll
            for (int i = 0; i < 4; ++i) a[i] = As[kk][tr * 4 + i];
#pragma unroll
            for (int j = 0; j < 4; ++j) b[j] = Bs[kk][tc * 4 + j];
#pragma unroll
            for (int i = 0; i < 4; ++i)
#pragma unroll
                for (int j = 0; j < 4; ++j) acc[i][j] += a[i] * b[j];
        }
        __syncthreads();
    }
#pragma unroll
    for (int i = 0; i < 4; ++i) {
        int row = n0 + tr * 4 + i;
#pragma unroll
        for (int j = 0; j < 4; ++j) {
            int col = j0 + tc * 4 + j;
            if (col < HC) OUT[(size_t)row * HC + col] = acc[i][j];
        }
    }
}

// ---------------- CSR build (hierarchical 3-pass scan) ----------------
__global__ void count_kernel(const int* __restrict__ dst, int* __restrict__ deg) {
    int e = blockIdx.x * blockDim.x + threadIdx.x;
    if (e < NE) atomicAdd(&deg[dst[e]], 1);
}
__global__ void scan_pass1(const int* __restrict__ deg, int* __restrict__ bsum) {
    __shared__ int red[256];
    int b = blockIdx.x, t = threadIdx.x;
    int lo = b * SCHUNK, hi = min(lo + SCHUNK, NN);
    int s = 0;
    for (int i = lo + t; i < hi; i += 256) s += deg[i] + 1;   // +1 self-loop
    red[t] = s;
    __syncthreads();
    for (int off = 128; off > 0; off >>= 1) {
        if (t < off) red[t] += red[t + off];
        __syncthreads();
    }
    if (t == 0) bsum[b] = red[0];
}
__global__ void scan_pass2(const int* __restrict__ bsum, int* __restrict__ boff,
                           int* __restrict__ rowptr) {
    __shared__ int lds[256];
    int t = threadIdx.x;
    int v0 = bsum[t];
    lds[t] = v0;
    __syncthreads();
    for (int off = 1; off < 256; off <<= 1) {
        int v = (t >= off) ? lds[t - off] : 0;
        __syncthreads();
        lds[t] += v;
        __syncthreads();
    }
    boff[t] = lds[t] - v0;          // exclusive
    if (t == 255) rowptr[NN] = lds[255];
}
__global__ void scan_pass3(const int* __restrict__ deg, const int* __restrict__ boff,
                           int* __restrict__ rowptr, int* __restrict__ cursor) {
    __shared__ int lds[256];
    int b = blockIdx.x, t = threadIdx.x;
    int i = b * SCHUNK + t;
    int d = (t < SCHUNK && i < NN) ? (deg[i] + 1) : 0;   // +1 self-loop
    lds[t] = d;
    __syncthreads();
    for (int off = 1; off < 256; off <<= 1) {
        int v = (t >= off) ? lds[t - off] : 0;
        __syncthreads();
        lds[t] += v;
        __syncthreads();
    }
    if (t < SCHUNK && i < NN) {
        int excl = lds[t] - d + boff[b];
        rowptr[i] = excl;
        cursor[i] = excl;
    }
}
__global__ void scatter_all(const int* __restrict__ src, const int* __restrict__ dst,
                            int* __restrict__ cursor, int* __restrict__ colsrc) {
    int e = blockIdx.x * blockDim.x + threadIdx.x;
    if (e < NE) {
        int pos = atomicAdd(&cursor[dst[e]], 1);
        colsrc[pos] = src[e];
    } else if (e < NE + NN) {
        int n = e - NE;
        int pos = atomicAdd(&cursor[n], 1);
        colsrc[pos] = n;
    }
}

// ---------------- pass A: softmax-aggregate xbn -> z[n, 32*CP] (bf16) ----------------
// Proven r21 form (block-per-node, CH=16, direct stores, conflicts 0).
// r29: small-CP layers (48/16) regrouped to J=8 channels x NG=CP/8 groups so the
// f32x4/uint2 path applies everywhere (was floatx2 + 4B scattered stores ->
// L3 agg at only 2.2 TB/s). Idle groups (g>=NG) still do staging/logits/
// reductions (required); only channel-partitioned accumulate/store is guarded.
// Per-channel edge order unchanged -> bit-identical.
template <int CIN, int CP>
__global__ __launch_bounds__(256) void agg_x(const unsigned short* __restrict__ xbn,
                                             const float* __restrict__ S,
                                             const int* __restrict__ rowptr,
                                             const int* __restrict__ colsrc,
                                             int n0, unsigned short* __restrict__ z) {
    constexpr int BS = 256, CH = 16;
    constexpr int J = (CP >= 64) ? (CP / 8) : 8;   // 16,12,8,8
    constexpr int NG = CP / J;                     // 8,8,6,2
    constexpr int NACC = J / 4;                    // 4,3,2,2
    constexpr int LIT = CH * 32 / 256;             // 2 logit iterations
    __shared__ __align__(16) float x_lds[CH * CP];
    __shared__ float w_lds[CH * 32];
    __shared__ int cs_lds[CH];
    __shared__ float red_m[8][32];
    __shared__ float red_s[8][32];

    int n = n0 + blockIdx.x;
    int tid = threadIdx.x;
    int start = rowptr[n], end = rowptr[n + 1];
    const int h = tid & 31, g = tid >> 5;
    const int cbase = g * J;
    const bool act = (g < NG);
    const float sd = S[(size_t)n * 64 + 32 + h];   // broadcast within head column

    float m_reg = -INFINITY, d_reg = 0.f;
    f32x4 acc4[NACC];
#pragma unroll
    for (int j = 0; j < NACC; ++j) acc4[j] = f32x4{0.f, 0.f, 0.f, 0.f};

    for (int chunk = start; chunk < end; chunk += CH) {
        int ce = min(CH, end - chunk);
        int ce32 = ce * 32;
        if (tid < CH && tid < ce) cs_lds[tid] = colsrc[chunk + tid];
        __syncthreads();   // B1: cs_lds visible

        float lreg[LIT];
        float pmx = -INFINITY;
#pragma unroll
        for (int p = 0; p < LIT; ++p) {
            int idx = p * 256 + tid;
            lreg[p] = -INFINITY;
            if (idx < ce32) {
                int e = idx >> 5;
                float l = S[(size_t)cs_lds[e] * 64 + h] + sd;
                l = l > 0.f ? l : 0.2f * l;
                lreg[p] = l;
                pmx = fmaxf(pmx, l);
            }
        }
        red_m[g][h] = pmx;
        // stage x rows (bf16 -> f32) via uint2, f32x4 stores
        for (int idx = tid; idx < ce * (CP / 4); idx += BS) {
            int e = idx / (CP / 4), c4 = idx % (CP / 4);
            uint2 u = reinterpret_cast<const uint2*>(xbn)[(size_t)cs_lds[e] * (CP / 4) + c4];
            f32x4 t;
            t[0] = __uint_as_float(u.x << 16);
            t[1] = __uint_as_float(u.x & 0xFFFF0000u);
            t[2] = __uint_as_float(u.y << 16);
            t[3] = __uint_as_float(u.y & 0xFFFF0000u);
            *reinterpret_cast<f32x4*>(&x_lds[e * CP + 4 * c4]) = t;
        }
        __syncthreads();   // B2: red_m + x_lds visible

        // per-thread redundant max reduce (identical order to serial version)
        float cm = red_m[0][h];
#pragma unroll
        for (int s2 = 1; s2 < 8; ++s2) cm = fmaxf(cm, red_m[s2][h]);
        float newm = fmaxf(m_reg, cm);
        float r = (m_reg == -INFINITY) ? 0.f : __expf(m_reg - newm);
        m_reg = newm;

        float ps = 0.f;
#pragma unroll
        for (int p = 0; p < LIT; ++p) {
            int idx = p * 256 + tid;
            if (idx < ce32) {
                float v = __expf(lreg[p] - m_reg);
                w_lds[idx] = v;
                ps += v;
            }
        }
        red_s[g][h] = ps;
        __syncthreads();   // B3: w_lds + red_s visible

        float ss = red_s[0][h];
#pragma unroll
        for (int s2 = 1; s2 < 8; ++s2) ss += red_s[s2][h];
        d_reg = d_reg * r + ss;

        if (act) {
            f32x4 rr4 = {r, r, r, r};
#pragma unroll
            for (int j = 0; j < NACC; ++j) acc4[j] *= rr4;
            for (int e = 0; e < ce; ++e) {
                float w = w_lds[e * 32 + h];
                f32x4 w4 = {w, w, w, w};
                const f32x4* xv = reinterpret_cast<const f32x4*>(&x_lds[e * CP + cbase]);
#pragma unroll
                for (int j = 0; j < NACC; ++j) acc4[j] += w4 * xv[j];
            }
        }
    }

    if (act) {
        float dinv = 1.f / d_reg;
        uint2* zp = reinterpret_cast<uint2*>(
            z + (size_t)(n - n0) * (32 * CP) + h * CP + cbase);
#pragma unroll
        for (int j = 0; j < NACC; ++j) {
            uint2 t;
            t.x = cvt_pk_bf16(acc4[j][0] * dinv, acc4[j][1] * dinv);
            t.y = cvt_pk_bf16(acc4[j][2] * dinv, acc4[j][3] * dinv);
            zp[j] = t;
        }
    }
}

// ---------------- pass B: LDS-tiled MFMA GEMM (MT=64) ----------------
// runtime nr (row count) + pstride (pbuf part stride, rows). FB path optionally
// emits per-channel BN stat partials (NT==1) via a deterministic LDS tree.
template <int NT, int KP, int KS, bool FB, bool STATS>
__global__ __launch_bounds__(256) void gemm_z_t(const unsigned short* __restrict__ z,
                                                const unsigned short* __restrict__ Wt,
                                                float* __restrict__ obuf,
                                                const float* __restrict__ bias,
                                                int n0, int COUT, int nr, int pstride,
                                                float* __restrict__ statp) {
    constexpr int NP = NT * 16;
    constexpr int KSEG = KP / KS;       // multiple of 64
    constexpr int NC = KSEG / 64;
    constexpr int MT = 64;
    __shared__ unsigned short Abuf[2][MT * 64];
    __shared__ unsigned short Bbuf[2][NP * 64];

    const int m0 = blockIdx.x * MT;
    const int kbeg = blockIdx.y * KSEG;
    const int tid = threadIdx.x;
    const int wv = tid >> 6;
    const int lane = tid & 63;
    const int mm = lane & 15, quad = lane >> 4;

    auto stage = [&](int buf, int kk) {
#pragma unroll
        for (int it = 0; it < 2; ++it) {
            int gi = it * 256 + tid;
            int row = gi >> 3, gc = gi & 7;
            int srow = m0 + row;
            if (srow > nr - 1) srow = nr - 1;
            const unsigned short* src = z + (size_t)srow * KP + kk + gc * 8;
            unsigned short* dst = &Abuf[buf][(size_t)(it * 256 + wv * 64) * 8];
            load_lds16(src, dst);
        }
#pragma unroll
        for (int it = 0; it < (NP * 8 + 255) / 256; ++it) {
            int gi = it * 256 + tid;
            if (gi < NP * 8) {
                int row = gi >> 3, gc = gi & 7;
                const unsigned short* src = Wt + (size_t)row * KP + kk + gc * 8;
                unsigned short* dst = &Bbuf[buf][(size_t)(it * 256 + wv * 64) * 8];
                load_lds16(src, dst);
            }
        }
    };

    f32x4 acc[NT];
#pragma unroll
    for (int t = 0; t < NT; ++t) acc[t] = f32x4{0.f, 0.f, 0.f, 0.f};

    stage(0, kbeg);
    for (int c = 0; c < NC; ++c) {
        asm volatile("s_waitcnt vmcnt(0)" ::: "memory");
        __syncthreads();
        int cur = c & 1;
        if (c + 1 < NC) stage(cur ^ 1, kbeg + (c + 1) * 64);
        const unsigned short* Ab = Abuf[cur];
        const unsigned short* Bb = Bbuf[cur];
#pragma unroll
        for (int hh = 0; hh < 2; ++hh) {
            bf16x8 a0 = *reinterpret_cast<const bf16x8*>(&Ab[(wv * 16 + mm) * 64 + hh * 32 + quad * 8]);
#pragma unroll
            for (int t = 0; t < NT; ++t) {
                bf16x8 b = *reinterpret_cast<const bf16x8*>(&Bb[(t * 16 + mm) * 64 + hh * 32 + quad * 8]);
                acc[t] = __builtin_amdgcn_mfma_f32_16x16x32_bf16(a0, b, acc[t], 0, 0, 0);
            }
        }
        __syncthreads();
    }

    int row0 = quad * 4;
    if constexpr (FB) {
        float s = 0.f, q = 0.f;
#pragma unroll
        for (int t = 0; t < NT; ++t) {
            int cc = t * 16 + mm;
#pragma unroll
            for (int r = 0; r < 4; ++r) {
                int m = m0 + wv * 16 + row0 + r;
                if (m < nr && cc < COUT) {
                    float v = acc[t][r] + bias[cc];
                    v = v > 0.f ? v : 0.01f * v;
                    obuf[(size_t)(n0 + m) * COUT + cc] = v;
                    if constexpr (STATS) { s += v; q += v * v; }
                }
            }
        }
        if constexpr (STATS) {
            static_assert(NT == 1, "STATS path assumes NT==1");
            __shared__ float ssum[4][4][16], sqsum[4][4][16];
            ssum[wv][quad][mm] = s; sqsum[wv][quad][mm] = q;
            __syncthreads();
            if (tid < 16) {
                float S = 0.f, Q = 0.f;
#pragma unroll
                for (int a = 0; a < 4; ++a)
#pragma unroll
                    for (int b2 = 0; b2 < 4; ++b2) {
                        S += ssum[a][b2][tid]; Q += sqsum[a][b2][tid];
                    }
                if (tid < COUT) {
                    statp[(size_t)blockIdx.x * 2 * COUT + tid] = S;
                    statp[(size_t)blockIdx.x * 2 * COUT + COUT + tid] = Q;
                }
            }
        }
    } else {
        float* pb = obuf + (size_t)blockIdx.y * pstride * NP;
#pragma unroll
        for (int t = 0; t < NT; ++t) {
            int cc = t * 16 + mm;
#pragma unroll
            for (int r = 0; r < 4; ++r) {
                int m = m0 + wv * 16 + row0 + r;
                pb[(size_t)m * NP + cc] = acc[t][r];
            }
        }
    }
}

// reduce K-split partials + bias + leaky 0.01 -> xout (fully-parallel form;
// runtime nr rows + pstride part stride)
__global__ void reduce_parts(const float* __restrict__ pbuf, int KS, int NPAD, int COUT,
                             const float* __restrict__ bias, int n0, int nr, int pstride,
                             float* __restrict__ xout) {
    int idx = blockIdx.x * blockDim.x + threadIdx.x;
    if (idx >= nr * NPAD) return;
    int m = idx / NPAD, c = idx % NPAD;
    if (c >= COUT) return;
    float s = 0.f;
    for (int p = 0; p < KS; ++p) s += pbuf[(size_t)p * pstride * NPAD + (size_t)m * NPAD + c];
    float v = s + bias[c];
    v = v > 0.f ? v : 0.01f * v;
    xout[(size_t)(n0 + m) * COUT + c] = v;
}

// ---------------- fused mean-pool + FC + sigmoid ----------------
__global__ __launch_bounds__(64) void pool_head(const float* __restrict__ x4,
                                                const int* __restrict__ batch,
                                                const float* __restrict__ cond,
                                                const float* __restrict__ fcW,
                                                const float* __restrict__ fcb,
                                                float* __restrict__ out) {
    int g = blockIdx.x;
    int lane = threadIdx.x;
    int lo = 0, hi = NN;
    while (lo < hi) { int mid = (lo + hi) >> 1; if (batch[mid] < g) lo = mid + 1; else hi = mid; }
    int lo2 = lo, hi2 = NN;
    while (lo2 < hi2) { int mid = (lo2 + hi2) >> 1; if (batch[mid] < g + 1) lo2 = mid + 1; else hi2 = mid; }
    int beg = lo, end = lo2;

    float s[5] = {0.f, 0.f, 0.f, 0.f, 0.f};
    for (int n = beg + lane; n < end; n += 64) {
#pragma unroll
        for (int c = 0; c < 5; ++c) s[c] += x4[(size_t)n * 5 + c];
    }
    float cz = 0.f;
    if (lane < 100) cz = cond[lane] * fcW[5 + lane];
    if (lane + 64 < 100) cz += cond[lane + 64] * fcW[5 + lane + 64];
#pragma unroll
    for (int off = 32; off > 0; off >>= 1) {
#pragma unroll
        for (int c = 0; c < 5; ++c) s[c] += __shfl_down(s[c], off, 64);
        cz += __shfl_down(cz, off, 64);
    }
    if (lane == 0) {
        float cnt = fmaxf((float)(end - beg), 1.f);
        float zv = fcb[0] + cz;
#pragma unroll
        for (int c = 0; c < 5; ++c) zv += (s[c] / cnt) * fcW[c];
        out[g] = 1.f / (1.f + __expf(-zv));
    }
}

// ---------------- per-layer driver ----------------
struct LayerBufs {
    float* scale; float* shift;
    unsigned short* xbn; unsigned short* zbuf;
    float* Sbuf; float* pbuf; const int* rowptr; const int* colsrc;
};

template <int CIN, int CP, int COUT, int NP, int NT, int KS, int SLABS, int NB, bool OSTATS>
static void run_layer(const float* xin, const float* sp_in,
                      const float* Wf, const unsigned short* Wft,
                      const unsigned short* Wt,
                      const float* Bv, const float* G, const float* Be,
                      float* xout, float* statp, int pstride,
                      const LayerBufs& B, hipStream_t stream) {
    constexpr int KP = 32 * CP;
    constexpr int NPAD = NT * 16;
    constexpr int NR = NN / SLABS;
    constexpr int NTILE = (NR + 63) / 64;
    bn_apply_f<CIN, CP, NB><<<512, 256, 0, stream>>>(xin, sp_in, G, Be,
                                                     B.scale, B.shift, B.xbn);
    if constexpr (CP >= 64) {
        gemm_s<CP><<<NN / 64, 256, 0, stream>>>(B.xbn, Wft, B.Sbuf);
    } else {
        gemm_bn<<<dim3(1, NN / 64), 256, 0, stream>>>(xin, Wf, B.scale, B.shift, CIN, 64, B.Sbuf);
    }
    for (int s = 0; s < SLABS; ++s) {
        int n0 = s * NR;
        agg_x<CIN, CP><<<NR, 256, 0, stream>>>(B.xbn, B.Sbuf, B.rowptr, B.colsrc, n0, B.zbuf);
        if constexpr (KS > 1) {
            gemm_z_t<NT, KP, KS, false, false><<<dim3(NTILE, KS), 256, 0, stream>>>(
                B.zbuf, Wt, B.pbuf, nullptr, n0, COUT, NR, pstride, nullptr);
            reduce_parts<<<((size_t)NR * NPAD + 255) / 256, 256, 0, stream>>>(
                B.pbuf, KS, NPAD, COUT, Bv, n0, NR, pstride, xout);
        } else {
            gemm_z_t<NT, KP, 1, true, OSTATS><<<dim3(NTILE, 1), 256, 0, stream>>>(
                B.zbuf, Wt, xout, Bv, n0, COUT, NR, pstride, statp);
        }
    }
}

extern "C" void kernel_launch(void* const* d_in, const int* in_sizes, int n_in,
                              void* d_out, int out_size, void* d_ws, size_t ws_size,
                              hipStream_t stream) {
    (void)in_sizes; (void)n_in; (void)out_size;
    const float* x     = (const float*)d_in[0];
    const int*   ei    = (const int*)d_in[1];
    const int*   batch = (const int*)d_in[2];
    const float* cond  = (const float*)d_in[3];
    const float* W[4]  = {(const float*)d_in[4],  (const float*)d_in[8],
                          (const float*)d_in[12], (const float*)d_in[16]};
    const float* Asp[4] = {(const float*)d_in[5],  (const float*)d_in[9],
                           (const float*)d_in[13], (const float*)d_in[17]};
    const float* Adp[4] = {(const float*)d_in[6],  (const float*)d_in[10],
                           (const float*)d_in[14], (const float*)d_in[18]};
    const float* Bv[4]  = {(const float*)d_in[7],  (const float*)d_in[11],
                           (const float*)d_in[15], (const float*)d_in[19]};
    const float* G[4]   = {(const float*)d_in[20], (const float*)d_in[22],
                           (const float*)d_in[24], (const float*)d_in[26]};
    const float* Be[4]  = {(const float*)d_in[21], (const float*)d_in[23],
                           (const float*)d_in[25], (const float*)d_in[27]};
    const float* fcW = (const float*)d_in[30];
    const float* fcb = (const float*)d_in[31];
    float* out = (float*)d_out;

    const int CPs[4]  = {128, 96, 48, 16};
    const int NPs[4]  = {96, 48, 16, 16};
    const int CINs[4] = {128, 90, 45, 15};
    const int COUTs[4] = {90, 45, 15, 5};

    // r29 layout modes: big (all single-slab, zbuf 328MB), mid (L1 2-slab,
    // L2-L4 single-slab, zbuf 246MB), small (r27 fallback, zbuf 164MB).
    auto layout_total = [&](size_t zb, size_t pb) -> size_t {
        size_t o = 0;
        auto a = [&](size_t b) { o += (b + 255) & ~(size_t)255; };
        a(zb); a((size_t)NN * 128 * 2); a(pb); a((size_t)NN * 90 * 4);
        a((size_t)NN * 64 * 4); a((size_t)NPB * 2 * 128 * 4); a((size_t)NPB * 2 * 128 * 4);
        a(128 * 4); a(128 * 4);
        for (int i = 0; i < 4; ++i) {
            a((size_t)CPs[i] * 64 * 4); a((size_t)64 * CPs[i] * 2);
            a((size_t)NPs[i] * 32 * CPs[i] * 2);
        }
        a((size_t)NN * 4); a((size_t)(NN + 1) * 4); a((size_t)NN * 4);
        a((size_t)(NE + NN) * 4); a((size_t)SCB * 4); a((size_t)SCB * 4);
        return o;
    };
    const size_t zb_big = (size_t)NN * 4096 * 2, pb_big = (size_t)4 * MPADX * 96 * 4;
    const size_t zb_mid = (size_t)NN * 3072 * 2;
    const size_t pb_mid = (size_t)4 * MPAD * 96 * 4;   // covers L1 2-slab KS=4 and L2 1-slab KS=3
    const size_t zb_sm  = (size_t)NSLAB * 4096 * 2, pb_sm = (size_t)4 * MPAD * 96 * 4;
    int mode = 2;   // 0=big, 1=mid, 2=small
    if (layout_total(zb_big, pb_big) <= ws_size) mode = 0;
    else if (layout_total(zb_mid, pb_mid) <= ws_size) mode = 1;
    const size_t zb = (mode == 0) ? zb_big : (mode == 1) ? zb_mid : zb_sm;
    const size_t pbb = (mode == 0) ? pb_big : (mode == 1) ? pb_mid : pb_sm;

    char* base = (char*)d_ws;
    size_t off = 0;
    auto alloc = [&](size_t b) {
        size_t o = off;
        off += (b + 255) & ~(size_t)255;
        return (void*)(base + o);
    };
    unsigned short* zbuf = (unsigned short*)alloc(zb);
    unsigned short* xbn  = (unsigned short*)alloc((size_t)NN * 128 * 2);
    float* pbuf    = (float*)alloc(pbb);
    float* xbuf    = (float*)alloc((size_t)NN * 90 * 4);
    float* Sbuf    = (float*)alloc((size_t)NN * 64 * 4);
    float* partial = (float*)alloc((size_t)NPB * 2 * 128 * 4);
    float* stat1   = (float*)alloc((size_t)NPB * 2 * 128 * 4);
    float* scale   = (float*)alloc(128 * 4);
    float* shift   = (float*)alloc(128 * 4);
    float* Wf_a[4]; unsigned short* Wft_a[4]; unsigned short* Wt_a[4];
    for (int i = 0; i < 4; ++i) {
        Wf_a[i]  = (float*)alloc((size_t)CPs[i] * 64 * 4);
        Wft_a[i] = (unsigned short*)alloc((size_t)64 * CPs[i] * 2);
        Wt_a[i]  = (unsigned short*)alloc((size_t)NPs[i] * 32 * CPs[i] * 2);
    }
    int* deg     = (int*)alloc((size_t)NN * 4);
    int* rowptr  = (int*)alloc((size_t)(NN + 1) * 4);
    int* cursor  = (int*)alloc((size_t)NN * 4);
    int* colsrc  = (int*)alloc((size_t)(NE + NN) * 4);
    int* bsum    = (int*)alloc((size_t)SCB * 4);
    int* boff    = (int*)alloc((size_t)SCB * 4);
    if (off > ws_size) return;

    const int* srcp = ei;
    const int* dstp = ei + NE;

    // all-layer weight prep in one dispatch, first (independent of everything)
    PrepArgs PA;
    int bb = 0;
    for (int i = 0; i < 4; ++i) {
        PA.L[i] = PrepLayer{W[i], Asp[i], Adp[i], Wf_a[i], Wft_a[i], Wt_a[i],
                            CINs[i], CPs[i], COUTs[i], NPs[i], bb};
        bb += CPs[i] + NPs[i];
    }
    PA.nb = bb;
    prep_all<<<bb, 256, 0, stream>>>(PA);

    // CSR by dst (hierarchical scan); deg zeroed via memset, self-loop +1 in scans
    hipMemsetAsync(deg, 0, (size_t)NN * 4, stream);
    count_kernel<<<(NE + 255) / 256, 256, 0, stream>>>(dstp, deg);
    scan_pass1<<<SCB, 256, 0, stream>>>(deg, bsum);
    scan_pass2<<<1, 256, 0, stream>>>(bsum, boff, rowptr);
    scan_pass3<<<SCB, 256, 0, stream>>>(deg, boff, rowptr, cursor);
    scatter_all<<<(NE + NN + 255) / 256, 256, 0, stream>>>(srcp, dstp, cursor, colsrc);

    LayerBufs B{scale, shift, xbn, zbuf, Sbuf, pbuf, rowptr, colsrc};

    bn_partial<<<NPB, 128, 0, stream>>>(x, NN, 128, partial);
    if (mode == 0) {
        run_layer<128, 128, 90, 96, 6, 4, 1, NPB, false>(x, partial,
            Wf_a[0], Wft_a[0], Wt_a[0], Bv[0], G[0], Be[0], xbuf, nullptr, MPADX, B, stream);
        bn_partial<<<NPB, 128, 0, stream>>>(xbuf, NN, 90, partial);
        run_layer< 90,  96, 45, 48, 3, 3, 1, NPB, false>(xbuf, partial,
            Wf_a[1], Wft_a[1], Wt_a[1], Bv[1], G[1], Be[1], xbuf, nullptr, MPADX, B, stream);
    } else if (mode == 1) {
        run_layer<128, 128, 90, 96, 6, 4, 2, NPB, false>(x, partial,
            Wf_a[0], Wft_a[0], Wt_a[0], Bv[0], G[0], Be[0], xbuf, nullptr, MPAD, B, stream);
        bn_partial<<<NPB, 128, 0, stream>>>(xbuf, NN, 90, partial);
        run_layer< 90,  96, 45, 48, 3, 3, 1, NPB, false>(xbuf, partial,
            Wf_a[1], Wft_a[1], Wt_a[1], Bv[1], G[1], Be[1], xbuf, nullptr, MPADX, B, stream);
    } else {
        run_layer<128, 128, 90, 96, 6, 4, 2, NPB, false>(x, partial,
            Wf_a[0], Wft_a[0], Wt_a[0], Bv[0], G[0], Be[0], xbuf, nullptr, MPAD, B, stream);
        bn_partial<<<NPB, 128, 0, stream>>>(xbuf, NN, 90, partial);
        run_layer< 90,  96, 45, 48, 3, 3, 2, NPB, false>(xbuf, partial,
            Wf_a[1], Wft_a[1], Wt_a[1], Bv[1], G[1], Be[1], xbuf, nullptr, MPAD, B, stream);
    }
    bn_partial<<<NPB, 128, 0, stream>>>(xbuf, NN, 45, partial);
    run_layer< 45,  48, 15, 16, 1, 1, 1, NPB, true >(xbuf, partial,
        Wf_a[2], Wft_a[2], Wt_a[2], Bv[2], G[2], Be[2], xbuf, stat1, MPADX, B, stream);
    run_layer< 15,  16,  5, 16, 1, 1, 1, 625, false>(xbuf, stat1,
        Wf_a[3], Wft_a[3], Wt_a[3], Bv[3], G[3], Be[3], xbuf, nullptr, MPADX, B, stream);

    pool_head<<<256, 64, 0, stream>>>(xbuf, batch, cond, fcW, fcb, out);
}